// Round 8
// baseline (532.405 us; speedup 1.0000x reference)
//
#include <hip/hip_runtime.h>
#include <hip/hip_bf16.h>
#include <cstddef>
#include <cstdint>

#define BATCH 8
#define SEQ   2048
#define DEMB  1024
#define DQ    512

typedef __attribute__((ext_vector_type(8))) _Float16 f16x8;
typedef __attribute__((ext_vector_type(4))) float f32x4;

#define MFMA16(a, b, c) __builtin_amdgcn_mfma_f32_16x16x32_f16((a), (b), (c), 0, 0, 0)

#define GLDS16(gp, lp) __builtin_amdgcn_global_load_lds(                      \
    (const __attribute__((address_space(1))) void*)(gp),                      \
    (__attribute__((address_space(3))) void*)(lp), 16, 0, 0)

#define VM0_BAR()                                                             \
  asm volatile("s_waitcnt vmcnt(0)\n\ts_barrier" ::: "memory")
#define BAR()                                                                 \
  asm volatile("s_barrier" ::: "memory")
#define LGKM_BAR()                                                            \
  asm volatile("s_waitcnt lgkmcnt(0)\n\ts_barrier" ::: "memory")

// ---------------------------------------------------------------------------
// Transpose W (fp32 [k][n]) -> WT (fp16 [n][k]) for all three weight mats.
// ---------------------------------------------------------------------------
__global__ __launch_bounds__(256) void wprep(
    const float* __restrict__ Wq, const float* __restrict__ Wk,
    const float* __restrict__ Wv, _Float16* __restrict__ wt)
{
  int qidx = blockIdx.x * 256 + threadIdx.x;     // 0 .. 3*1024*128-1
  int w   = qidx >> 17;
  int rem = qidx & 131071;
  int k   = rem >> 7;                            // 0..1023
  int n   = (rem & 127) * 4;                     // 0..508
  const float* W = (w == 0) ? Wq : (w == 1) ? Wk : Wv;
  float4 v = *(const float4*)&W[(size_t)k * DQ + n];
  _Float16* dst = wt + (size_t)w * (DQ * DEMB);
  dst[(size_t)(n + 0) * DEMB + k] = (_Float16)v.x;
  dst[(size_t)(n + 1) * DEMB + k] = (_Float16)v.y;
  dst[(size_t)(n + 2) * DEMB + k] = (_Float16)v.z;
  dst[(size_t)(n + 3) * DEMB + k] = (_Float16)v.w;
}

// ---------------------------------------------------------------------------
// Projection GEMM, single-pass fp16 MFMA (r6 version: Q packed in 64-row
// groups: g=m>>6 at halfs [g*65536, +65536): hi 64x512 then lo 64x512).
// ---------------------------------------------------------------------------
__global__ __launch_bounds__(256) void proj_f16(
    const float* __restrict__ x, const _Float16* __restrict__ wt,
    _Float16* __restrict__ kf, _Float16* __restrict__ vt,
    _Float16* __restrict__ qpack)
{
  const int w  = blockIdx.z;
  const int mt = blockIdx.y, nt = blockIdx.x;

  __shared__ _Float16 Xs[128][40];
  __shared__ _Float16 Ws[128][40];

  const int tid  = threadIdx.x;
  const int wave = tid >> 6, l = tid & 63;
  const int wm = wave >> 1, wn = wave & 1;
  const int lo4 = l & 15, hi2 = l >> 4;

  f32x4 acc[4][4];
  #pragma unroll
  for (int mf = 0; mf < 4; mf++)
    #pragma unroll
    for (int nf = 0; nf < 4; nf++)
      #pragma unroll
      for (int i = 0; i < 4; i++) acc[mf][nf][i] = 0.f;

  const int    srow  = tid >> 1;
  const int    skh   = (tid & 1) * 16;
  const size_t xbase = (size_t)(mt * 128 + srow) * DEMB + skh;
  const size_t wbase = (size_t)w * (DQ * DEMB) + (size_t)(nt * 128 + srow) * DEMB + skh;

  #pragma unroll 1
  for (int k0 = 0; k0 < DEMB; k0 += 32) {
    #pragma unroll
    for (int i = 0; i < 2; i++) {
      float4 t0 = *(const float4*)&x[xbase + k0 + i * 8];
      float4 t1 = *(const float4*)&x[xbase + k0 + i * 8 + 4];
      f16x8 hv;
      hv[0] = (_Float16)t0.x; hv[1] = (_Float16)t0.y;
      hv[2] = (_Float16)t0.z; hv[3] = (_Float16)t0.w;
      hv[4] = (_Float16)t1.x; hv[5] = (_Float16)t1.y;
      hv[6] = (_Float16)t1.z; hv[7] = (_Float16)t1.w;
      *(f16x8*)&Xs[srow][skh + i * 8] = hv;
    }
    *(f16x8*)&Ws[srow][skh]     = *(const f16x8*)&wt[wbase + k0];
    *(f16x8*)&Ws[srow][skh + 8] = *(const f16x8*)&wt[wbase + k0 + 8];
    __syncthreads();

    f16x8 a[4], bfr[4];
    #pragma unroll
    for (int mf = 0; mf < 4; mf++)
      a[mf] = *(const f16x8*)&Xs[wm*64 + mf*16 + lo4][hi2*8];
    #pragma unroll
    for (int nf = 0; nf < 4; nf++)
      bfr[nf] = *(const f16x8*)&Ws[wn*64 + nf*16 + lo4][hi2*8];
    #pragma unroll
    for (int mf = 0; mf < 4; mf++)
      #pragma unroll
      for (int nf = 0; nf < 4; nf++)
        acc[mf][nf] = MFMA16(a[mf], bfr[nf], acc[mf][nf]);
    __syncthreads();
  }

  const int mb = mt * 128 + wm * 64;
  const int nb = nt * 128 + wn * 64;
  #pragma unroll
  for (int mf = 0; mf < 4; mf++)
    #pragma unroll
    for (int nf = 0; nf < 4; nf++)
      #pragma unroll
      for (int i = 0; i < 4; i++) {
        int m = mb + mf*16 + hi2*4 + i;
        int n = nb + nf*16 + lo4;
        float val = acc[mf][nf][i];
        if (w == 0) {
          _Float16 h  = (_Float16)val;
          _Float16 lo = (_Float16)(val - (float)h);
          size_t base = (size_t)(m >> 6) * 65536 + (size_t)(m & 63) * 512 + n;
          qpack[base]         = h;
          qpack[base + 32768] = lo;
        } else if (w == 1) {
          kf[(size_t)m * 512 + n] = (_Float16)val;
        } else {
          vt[(size_t)(m >> 11) * (512 * 2048) + (size_t)n * 2048 + (m & 2047)]
              = (_Float16)val;
        }
      }
}

// ---------------------------------------------------------------------------
// Flash attention v6. 512 threads = 8 waves; 64 q-rows; 64-key tiles (32 kt).
// Wave (qw=w&3 -> 16 q-rows, kw=w>>2 -> 32-key half / d-interleave).
// Q-hi in regs; Q-lo in LDS (staged once, XOR-swizzled bits6-8);
// K staged in half-d double buffers via global_load_lds, source-swizzled
// with ((row>>1)&7)<<6 (conflict-free ds_read_b128 by slot arithmetic);
// V read DIRECT from L2 (full 64B-line utilization, XCD-pinned batch);
// QK uses 4 accumulator chains (hi/lo split). 3 barriers/kt, no counted
// vmcnt stalls (K halves staged 1.5-2 phases ahead; compiler's PV-tail
// drain is the only sync).
// ---------------------------------------------------------------------------
__global__ __launch_bounds__(512, 2) void flash_v6(
    const _Float16* __restrict__ kfp, const _Float16* __restrict__ vtp,
    const int* __restrict__ maskg,
    float* dout)                          // aliases Q storage - no restrict
{
  const int bb = blockIdx.x & 7;          // batch -> XCD pin
  const int qt = blockIdx.x >> 3;         // 0..31
  const int q0 = qt * 64;

  const int tid = threadIdx.x;
  const int w = tid >> 6, l = tid & 63;
  const int qw = w & 3;                   // 16-row group
  const int kw = w >> 2;                  // 0..1
  const int lo4 = l & 15, hi2 = l >> 4;

  __shared__ _Float16 Kst[2][64][256];    // 64KB, src-swz ((row>>1)&7)<<6
  __shared__ _Float16 Qlo[64 * 512];      // 64KB, src-swz ((row&7))<<6
  __shared__ _Float16 P[64 * 64];         // 8KB, row-swz (row&7)<<4
  __shared__ int      Msk[2048];          // 8KB
  __shared__ float pmax[2][64], psum[2][64];

  const _Float16* qpk = (const _Float16*)dout + (size_t)(bb * 32 + qt) * 65536;
  const char*     kb  = (const char*)(kfp + (size_t)bb * SEQ * 512);
  const _Float16* vtb = vtp + (size_t)bb * (512 * 2048);

  const _Float16* qhi = qpk + (size_t)(qw * 16 + lo4) * 512;

  // stage K half H (64 rows x 256 halfs = 32KB) of tile KT into Kst[B]
#define STAGE_K(KT, H, B) do {                                                \
    const char* kg_ = kb + (size_t)(KT) * 64 * 1024;                          \
    char* lb_ = (char*)&Kst[(B)][0][0];                                       \
    _Pragma("unroll")                                                         \
    for (int i_ = 0; i_ < 4; i_++) {                                          \
      int D_ = i_ * 8192 + tid * 16;                                          \
      int row_ = D_ >> 9, cb_ = D_ & 511;                                     \
      GLDS16(kg_ + (size_t)row_ * 1024 + (H) * 512 +                          \
                 (cb_ ^ (((row_ >> 1) & 7) << 6)),                            \
             lb_ + D_);                                                       \
    } } while (0)

  // QK d-half H from Kst[B]; 4 chains (Sh hi-pass, Sl lo-pass)
#define QK_HALF(H, B) do {                                                    \
    const char* kl_ = (const char*)&Kst[(B)][0][0];                           \
    const int r0_ = kw * 32 + lo4, r1_ = r0_ + 16;                            \
    const int ksw_ = ((r0_ >> 1) & 7) << 6;                                   \
    _Pragma("unroll")                                                         \
    for (int s_ = 0; s_ < 8; s_++) {                                          \
      const int dby_ = s_ * 64 + hi2 * 16;                                    \
      f16x8 k0 = *(const f16x8*)(kl_ + r0_ * 512 + (dby_ ^ ksw_));            \
      f16x8 k1 = *(const f16x8*)(kl_ + r1_ * 512 + (dby_ ^ ksw_));            \
      f16x8 qv = *(const f16x8*)(qlb + ((((H) * 512) + dby_) ^ qsw));         \
      __builtin_amdgcn_s_setprio(1);                                          \
      Sh[0] = MFMA16(fq[(H) * 8 + s_], k0, Sh[0]);                            \
      Sh[1] = MFMA16(fq[(H) * 8 + s_], k1, Sh[1]);                            \
      Sl[0] = MFMA16(qv, k0, Sl[0]);                                          \
      Sl[1] = MFMA16(qv, k1, Sl[1]);                                          \
      __builtin_amdgcn_s_setprio(0);                                          \
    } } while (0)

  // ---- prologue ----
  {
    int4 mv = *(const int4*)&maskg[bb * SEQ + tid * 4];
    *(int4*)&Msk[tid * 4] = mv;
  }
  f16x8 fq[16];
  #pragma unroll
  for (int st = 0; st < 16; st++)
    fq[st] = *(const f16x8*)(qhi + st * 32 + hi2 * 8);

  // Q-lo plane -> LDS (swizzled source), 8 GLDS/thread
  {
    const char* qg = (const char*)qpk + 65536;      // lo plane
    char* lb = (char*)Qlo;
    #pragma unroll
    for (int i_ = 0; i_ < 8; i_++) {
      int D_ = i_ * 8192 + tid * 16;
      int row_ = D_ >> 10, off_ = D_ & 1023;
      GLDS16(qg + (size_t)row_ * 1024 + (off_ ^ ((row_ & 7) << 6)), lb + D_);
    }
  }
  STAGE_K(0, 0, 0);
  STAGE_K(0, 1, 1);
  __syncthreads();                        // full drain

  const char* qlb = (const char*)Qlo + (size_t)(qw * 16 + lo4) * 1024;
  const int   qsw = (lo4 & 7) << 6;

  f32x4 o[16];
  #pragma unroll
  for (int f = 0; f < 16; f++)
    #pragma unroll
    for (int i = 0; i < 4; i++) o[f][i] = 0.f;

  float m_run[4], l_run[4], m_runP = -3.0e38f;
  #pragma unroll
  for (int i = 0; i < 4; i++) { m_run[i] = -3.0e38f; l_run[i] = 0.f; }

  #pragma unroll 1
  for (int kt = 0; kt < 32; kt++) {
    const int key0 = kt * 64;

    f32x4 Sh[2], Sl[2];
    #pragma unroll
    for (int f = 0; f < 2; f++)
      #pragma unroll
      for (int i = 0; i < 4; i++) { Sh[f][i] = 0.f; Sl[f][i] = 0.f; }

    // ---- P1: all staged K complete; QK half0 ----
    VM0_BAR();
    QK_HALF(0, 0);

    // ---- P2: QK half1; stage next-kt half0; softmax-local ----
    BAR();
    STAGE_K(kt + 1, 0, 0);                // buf0 free (QK0 done by all waves)
    QK_HALF(1, 1);

    const int ms0 = Msk[key0 + kw * 32 + lo4];
    const int ms1 = Msk[key0 + kw * 32 + 16 + lo4];
    f32x4 S[2];
    #pragma unroll
    for (int f = 0; f < 2; f++)
      #pragma unroll
      for (int i = 0; i < 4; i++) S[f][i] = Sh[f][i] + Sl[f][i];

    #pragma unroll
    for (int i = 0; i < 4; i++) {
      if (!ms0) S[0][i] = -1.0e9f;
      if (!ms1) S[1][i] = -1.0e9f;
      float mx = fmaxf(S[0][i], S[1][i]);
      #pragma unroll
      for (int off = 1; off < 16; off <<= 1)
        mx = fmaxf(mx, __shfl_xor(mx, off, 64));
      float p0 = __expf(S[0][i] - mx);
      float p1 = __expf(S[1][i] - mx);
      int row = qw*16 + hi2*4 + i;
      int swz = (row & 7) << 4;
      int b0  = (row*128 + (kw*32 + lo4)*2) ^ swz;
      int b1  = (row*128 + (kw*32 + 16 + lo4)*2) ^ swz;
      *(_Float16*)((char*)P + b0) = (_Float16)p0;
      *(_Float16*)((char*)P + b1) = (_Float16)p1;
      float ps = p0 + p1;
      #pragma unroll
      for (int off = 1; off < 16; off <<= 1) ps += __shfl_xor(ps, off, 64);
      if (lo4 == 0) { pmax[kw][row] = mx; psum[kw][row] = ps; }
    }

    // ---- P3: publish P + stats (K prefetch stays in flight) ----
    LGKM_BAR();

    // ---- P4: stage next-kt half1; merge stats; rescale; PV (V direct) ----
    STAGE_K(kt + 1, 1, 1);                // buf1 free (QK1 done by all waves)

    float oscale[4];
    #pragma unroll
    for (int i = 0; i < 4; i++) {
      int row = qw*16 + hi2*4 + i;
      float m0 = pmax[0][row], m1 = pmax[1][row];
      float s0 = psum[0][row], s1 = psum[1][row];
      float mn = fmaxf(m_run[i], fmaxf(m0, m1));
      oscale[i] = __expf(m_run[i] - mn);
      l_run[i] = l_run[i] * oscale[i]
               + __expf(m0 - mn) * s0 + __expf(m1 - mn) * s1;
      m_run[i] = mn;
    }
    #pragma unroll
    for (int f = 0; f < 16; f++)
      #pragma unroll
      for (int i = 0; i < 4; i++) o[f][i] *= oscale[i];

    f16x8 pa[2];
    {
      const int prow = qw*16 + lo4;
      float m0p = pmax[0][prow], m1p = pmax[1][prow];
      float mnp = fmaxf(m_runP, fmaxf(m0p, m1p));
      m_runP = mnp;
      _Float16 c0 = (_Float16)__expf(m0p - mnp);
      _Float16 c1 = (_Float16)__expf(m1p - mnp);
      const int psw = (prow & 7) << 4;
      pa[0] = *(const f16x8*)((const char*)P + prow*128 + ((hi2*16) ^ psw));
      pa[1] = *(const f16x8*)((const char*)P + prow*128 + ((64 + hi2*16) ^ psw));
      pa[0] = pa[0] * c0;
      pa[1] = pa[1] * c1;
    }

    {
      const _Float16* vkb = vtb + key0 + hi2 * 8;
      #pragma unroll
      for (int h = 0; h < 2; h++)
        #pragma unroll
        for (int j = 0; j < 8; j++) {
          const int d = h*256 + j*32 + kw*16 + lo4;
          const _Float16* vp = vkb + (size_t)d * 2048;
          f16x8 v0 = *(const f16x8*)(vp);
          f16x8 v1 = *(const f16x8*)(vp + 32);
          __builtin_amdgcn_s_setprio(1);
          o[h*8+j] = MFMA16(pa[0], v0, o[h*8+j]);
          o[h*8+j] = MFMA16(pa[1], v1, o[h*8+j]);
          __builtin_amdgcn_s_setprio(0);
        }
    }
  }
#undef STAGE_K
#undef QK_HALF

  asm volatile("s_waitcnt vmcnt(0)" ::: "memory");

  // ---- epilogue: normalize and store (overwrites block's own Q region) ----
  #pragma unroll
  for (int i = 0; i < 4; i++) {
    float inv = 1.0f / l_run[i];
    int rowg = bb * SEQ + q0 + qw*16 + hi2*4 + i;
    #pragma unroll
    for (int h = 0; h < 2; h++)
      #pragma unroll
      for (int j = 0; j < 8; j++) {
        int d = h*256 + j*32 + kw*16 + lo4;
        dout[(size_t)rowg * 512 + d] = o[h*8 + j][i] * inv;
      }
  }
}

extern "C" void kernel_launch(void* const* d_in, const int* in_sizes, int n_in,
                              void* d_out, int out_size, void* d_ws, size_t ws_size,
                              hipStream_t stream)
{
  const float* x    = (const float*)d_in[0];
  const float* Wq   = (const float*)d_in[1];
  const float* Wk   = (const float*)d_in[2];
  const float* Wv   = (const float*)d_in[3];
  const int*   mask = (const int*)d_in[4];

  _Float16* wsh = (_Float16*)d_ws;
  _Float16* KF = wsh;                  //  8,388,608 halfs (K fp16 [b*t][d])
  _Float16* VT = wsh + 8388608;        //  8,388,608 halfs (V^T fp16 [b][d][t])
  _Float16* WT = wsh + 16777216;       //  1,572,864 halfs -> 36.7 MB total

  wprep<<<1536, 256, 0, stream>>>(Wq, Wk, Wv, WT);

  dim3 pgrid(4, 128, 3);
  proj_f16<<<pgrid, 256, 0, stream>>>(x, WT, KF, VT, (_Float16*)d_out);

  flash_v6<<<256, 512, 0, stream>>>(KF, VT, mask, (float*)d_out);
}

// Round 9
// 400.321 us; speedup vs baseline: 1.3299x; 1.3299x over previous
//
#include <hip/hip_runtime.h>
#include <hip/hip_bf16.h>
#include <cstddef>
#include <cstdint>

#define BATCH 8
#define SEQ   2048
#define DEMB  1024
#define DQ    512

typedef __attribute__((ext_vector_type(8))) _Float16 f16x8;
typedef __attribute__((ext_vector_type(4))) float f32x4;

#define MFMA16(a, b, c) __builtin_amdgcn_mfma_f32_16x16x32_f16((a), (b), (c), 0, 0, 0)

#define GLDS16(gp, lp) __builtin_amdgcn_global_load_lds(                      \
    (const __attribute__((address_space(1))) void*)(gp),                      \
    (__attribute__((address_space(3))) void*)(lp), 16, 0, 0)

#define VM_BAR(N)                                                             \
  asm volatile("s_waitcnt vmcnt(" #N ")\n\ts_barrier" ::: "memory")
#define VM_LGKM_BAR(N)                                                        \
  asm volatile("s_waitcnt vmcnt(" #N ") lgkmcnt(0)\n\ts_barrier" ::: "memory")
#define LGKM_BAR()                                                            \
  asm volatile("s_waitcnt lgkmcnt(0)\n\ts_barrier" ::: "memory")

// ---------------------------------------------------------------------------
// Transpose W (fp32 [k][n]) -> WT (fp16 [n][k]) for all three weight mats.
// ---------------------------------------------------------------------------
__global__ __launch_bounds__(256) void wprep(
    const float* __restrict__ Wq, const float* __restrict__ Wk,
    const float* __restrict__ Wv, _Float16* __restrict__ wt)
{
  int qidx = blockIdx.x * 256 + threadIdx.x;     // 0 .. 3*1024*128-1
  int w   = qidx >> 17;
  int rem = qidx & 131071;
  int k   = rem >> 7;                            // 0..1023
  int n   = (rem & 127) * 4;                     // 0..508
  const float* W = (w == 0) ? Wq : (w == 1) ? Wk : Wv;
  float4 v = *(const float4*)&W[(size_t)k * DQ + n];
  _Float16* dst = wt + (size_t)w * (DQ * DEMB);
  dst[(size_t)(n + 0) * DEMB + k] = (_Float16)v.x;
  dst[(size_t)(n + 1) * DEMB + k] = (_Float16)v.y;
  dst[(size_t)(n + 2) * DEMB + k] = (_Float16)v.z;
  dst[(size_t)(n + 3) * DEMB + k] = (_Float16)v.w;
}

// ---------------------------------------------------------------------------
// Projection GEMM v3: BM=128, BN=128, BK=64, 256 thr = 4 waves of 64x64.
// Double-buffered LDS (64KB total -> 2 blocks/CU). W staged via
// global_load_lds (source-swizzled, both-sides); X staged global->reg->
// cvt->ds_write (T14 split: loads issued before compute, vmcnt(0)+write
// after). ONE barrier per K-tile (T3-minimum). Epilogue identical to r6.
// Q packed into d_out in 64-row groups (hi 64x512 then lo 64x512).
// ---------------------------------------------------------------------------
__global__ __launch_bounds__(256) void proj_v3(
    const float* __restrict__ x, const _Float16* __restrict__ wt,
    _Float16* __restrict__ kf, _Float16* __restrict__ vt,
    _Float16* __restrict__ qpack)
{
  const int w  = blockIdx.z;
  const int mt = blockIdx.y, nt = blockIdx.x;

  __shared__ _Float16 Xs[2][128 * 64];   // 16KB per buf
  __shared__ _Float16 Ws[2][128 * 64];   // 16KB per buf

  const int tid  = threadIdx.x;
  const int wave = tid >> 6, l = tid & 63;
  const int wm = wave >> 1, wn = wave & 1;
  const int lo4 = l & 15, hi2 = l >> 4;

  const int xrow  = tid >> 1;            // 0..127
  const int khalf = tid & 1;             // k sub-offset 0 / 32
  const float* xbase = x + (size_t)(mt * 128 + xrow) * DEMB + khalf * 32;

  f32x4 acc[4][4];
  #pragma unroll
  for (int mf = 0; mf < 4; mf++)
    #pragma unroll
    for (int nf = 0; nf < 4; nf++)
      #pragma unroll
      for (int i = 0; i < 4; i++) acc[mf][nf][i] = 0.f;

  float4 xr[8];

#define LOADX(T) do {                                                         \
    const float* xp_ = xbase + (T) * 64;                                      \
    _Pragma("unroll")                                                         \
    for (int j_ = 0; j_ < 8; j_++) xr[j_] = *(const float4*)(xp_ + j_ * 4);   \
  } while (0)

#define WRITEX(B) do {                                                        \
    char* lb_ = (char*)&Xs[(B)][0];                                           \
    const int rb_ = xrow * 128, sw_ = (xrow & 7) << 4;                        \
    _Pragma("unroll")                                                         \
    for (int j8_ = 0; j8_ < 4; j8_++) {                                       \
      f16x8 hv_;                                                              \
      float4 a_ = xr[j8_*2], b_ = xr[j8_*2 + 1];                              \
      hv_[0] = (_Float16)a_.x; hv_[1] = (_Float16)a_.y;                       \
      hv_[2] = (_Float16)a_.z; hv_[3] = (_Float16)a_.w;                       \
      hv_[4] = (_Float16)b_.x; hv_[5] = (_Float16)b_.y;                       \
      hv_[6] = (_Float16)b_.z; hv_[7] = (_Float16)b_.w;                       \
      *(f16x8*)(lb_ + rb_ + ((khalf*64 + j8_*16) ^ sw_)) = hv_;               \
    } } while (0)

#define STAGE_W(T, B) do {                                                    \
    char* lb_ = (char*)&Ws[(B)][0];                                           \
    _Pragma("unroll")                                                         \
    for (int i_ = 0; i_ < 4; i_++) {                                          \
      int D_ = i_ * 4096 + tid * 16;                                          \
      int row_ = D_ >> 7, cb_ = D_ & 127;                                     \
      const char* g_ = (const char*)wt +                                      \
          ((size_t)w * (DQ * DEMB) + (size_t)(nt*128 + row_) * DEMB +         \
           (T) * 64) * 2 + (cb_ ^ ((row_ & 7) << 4));                         \
      GLDS16(g_, lb_ + D_);                                                   \
    } } while (0)

#define COMPUTE(B) do {                                                       \
    const char* xl_ = (const char*)&Xs[(B)][0];                               \
    const char* wl_ = (const char*)&Ws[(B)][0];                               \
    _Pragma("unroll")                                                         \
    for (int ks_ = 0; ks_ < 2; ks_++) {                                       \
      f16x8 a_[4], b_[4];                                                     \
      _Pragma("unroll")                                                       \
      for (int mf_ = 0; mf_ < 4; mf_++) {                                     \
        int row_ = wm*64 + mf_*16 + lo4;                                      \
        a_[mf_] = *(const f16x8*)(xl_ + row_*128 +                            \
                    ((ks_*64 + hi2*16) ^ ((row_ & 7) << 4)));                 \
      }                                                                       \
      _Pragma("unroll")                                                       \
      for (int nf_ = 0; nf_ < 4; nf_++) {                                     \
        int row_ = wn*64 + nf_*16 + lo4;                                      \
        b_[nf_] = *(const f16x8*)(wl_ + row_*128 +                            \
                    ((ks_*64 + hi2*16) ^ ((row_ & 7) << 4)));                 \
      }                                                                       \
      __builtin_amdgcn_s_setprio(1);                                          \
      _Pragma("unroll")                                                       \
      for (int mf_ = 0; mf_ < 4; mf_++)                                       \
        _Pragma("unroll")                                                     \
        for (int nf_ = 0; nf_ < 4; nf_++)                                     \
          acc[mf_][nf_] = MFMA16(a_[mf_], b_[nf_], acc[mf_][nf_]);            \
      __builtin_amdgcn_s_setprio(0);                                          \
    } } while (0)

  // prologue: tile 0 into buf 0
  LOADX(0); STAGE_W(0, 0);
  asm volatile("s_waitcnt vmcnt(0)" ::: "memory");
  WRITEX(0);
  LGKM_BAR();

  #pragma unroll 2
  for (int t = 0; t < 16; t++) {
    const int cur = t & 1;
    if (t < 15) { LOADX(t + 1); STAGE_W(t + 1, cur ^ 1); }
    COMPUTE(cur);
    if (t < 15) {
      asm volatile("s_waitcnt vmcnt(0)" ::: "memory");   // xr ready, W landed
      WRITEX(cur ^ 1);
    }
    LGKM_BAR();                       // publish writes; all reads done
  }
#undef LOADX
#undef WRITEX
#undef STAGE_W
#undef COMPUTE

  // ---- epilogue (identical to r6 proj) ----
  const int mb = mt * 128 + wm * 64;
  const int nb = nt * 128 + wn * 64;
  #pragma unroll
  for (int mf = 0; mf < 4; mf++)
    #pragma unroll
    for (int nf = 0; nf < 4; nf++)
      #pragma unroll
      for (int i = 0; i < 4; i++) {
        int m = mb + mf*16 + hi2*4 + i;
        int n = nb + nf*16 + lo4;
        float val = acc[mf][nf][i];
        if (w == 0) {
          _Float16 h  = (_Float16)val;
          _Float16 lo = (_Float16)(val - (float)h);
          size_t base = (size_t)(m >> 6) * 65536 + (size_t)(m & 63) * 512 + n;
          qpack[base]         = h;
          qpack[base + 32768] = lo;
        } else if (w == 1) {
          kf[(size_t)m * 512 + n] = (_Float16)val;
        } else {
          vt[(size_t)(m >> 11) * (512 * 2048) + (size_t)n * 2048 + (m & 2047)]
              = (_Float16)val;
        }
      }
}

// ---------------------------------------------------------------------------
// Flash attention v4 (r6 VERBATIM — best measured: 258µs).
// Counted-vmcnt 4-phase pipeline, merged single-exchange softmax, Q hi+lo in
// registers, mask in LDS; per-kt global traffic is exclusively
// global_load_lds (exact vmcnt accounting 8/4/8+lgkm/4).
// ---------------------------------------------------------------------------
__global__ __launch_bounds__(512, 2) void flash_v4(
    const _Float16* __restrict__ kfp, const _Float16* __restrict__ vtp,
    const int* __restrict__ maskg,
    float* dout)                          // aliases Q storage - no restrict
{
  const int bb = blockIdx.x & 7;          // batch -> XCD pin
  const int qt = blockIdx.x >> 3;         // 0..31
  const int q0 = qt * 64;

  const int tid = threadIdx.x;
  const int w = tid >> 6, l = tid & 63;
  const int qw = w & 3;                   // 16-row group
  const int kw = w >> 2;                  // 0..1
  const int lo4 = l & 15, hi2 = l >> 4;

  __shared__ _Float16 Kst[2][64][256];    // 64KB, src-swizzled
  __shared__ _Float16 Vst[2][256][64];    // 64KB, src-swizzled
  __shared__ _Float16 P[64 * 64];         // 8KB, XOR-swizzled rows
  __shared__ int      Msk[2048];          // 8KB
  __shared__ float pmax[2][64], psum[2][64];

  const _Float16* qpk = (const _Float16*)dout + (size_t)(bb * 32 + qt) * 65536;
  const char*     kb  = (const char*)(kfp + (size_t)bb * SEQ * 512);
  const char*     vtb = (const char*)(vtp + (size_t)bb * (512 * 2048));

  const _Float16* qhi = qpk + (size_t)(qw * 16 + lo4) * 512;
  const _Float16* qlo = qhi + 32768;

#define STAGE_K(KT, H, B) do {                                                \
    const char* kg_ = kb + (size_t)(KT) * 64 * 1024;                          \
    char* lb_ = (char*)&Kst[(B)][0][0];                                       \
    _Pragma("unroll")                                                         \
    for (int i_ = 0; i_ < 4; i_++) {                                          \
      int D_ = i_ * 8192 + tid * 16;                                          \
      int row_ = D_ >> 9, cb_ = D_ & 511;                                     \
      GLDS16(kg_ + (size_t)row_ * 1024 + (H) * 512 +                          \
                 (cb_ ^ ((row_ & 7) << 4)),                                   \
             lb_ + D_);                                                       \
    } } while (0)

#define STAGE_V(KT, H, B) do {                                                \
    const char* vg_ = vtb + (size_t)(KT) * 128;                               \
    char* lb_ = (char*)&Vst[(B)][0][0];                                       \
    _Pragma("unroll")                                                         \
    for (int i_ = 0; i_ < 4; i_++) {                                          \
      int D_ = i_ * 8192 + tid * 16;                                          \
      int row_ = D_ >> 7, cb_ = D_ & 127;                                     \
      GLDS16(vg_ + (size_t)((H) * 256 + row_) * 4096 +                        \
                 (cb_ ^ ((row_ & 7) << 4)),                                   \
             lb_ + D_);                                                       \
    } } while (0)

#define QK_HALF(H, B) do {                                                    \
    const char* kl_ = (const char*)&Kst[(B)][0][0];                           \
    const int r0_ = kw * 32 + lo4, r1_ = r0_ + 16;                            \
    const int sw_ = (lo4 & 7) << 4;                                           \
    _Pragma("unroll")                                                         \
    for (int s_ = 0; s_ < 8; s_++) {                                          \
      const int dby_ = (s_ * 32 + hi2 * 8) * 2;                               \
      f16x8 k0 = *(const f16x8*)(kl_ + r0_ * 512 + (dby_ ^ sw_));             \
      f16x8 k1 = *(const f16x8*)(kl_ + r1_ * 512 + (dby_ ^ sw_));             \
      __builtin_amdgcn_s_setprio(1);                                          \
      S[0] = MFMA16(fq[(H) * 8 + s_], k0, S[0]);                              \
      S[1] = MFMA16(fq[(H) * 8 + s_], k1, S[1]);                              \
      S[0] = MFMA16(fql[(H) * 8 + s_], k0, S[0]);                             \
      S[1] = MFMA16(fql[(H) * 8 + s_], k1, S[1]);                             \
      __builtin_amdgcn_s_setprio(0);                                          \
    } } while (0)

#define PV_HALF(H, B) do {                                                    \
    const char* vl_ = (const char*)&Vst[(B)][0][0];                           \
    _Pragma("unroll")                                                         \
    for (int j_ = 0; j_ < 8; j_++) {                                          \
      const int dl_ = j_ * 32 + kw * 16 + lo4;                                \
      const int vs_ = (dl_ & 7) << 4;                                         \
      f16x8 v0 = *(const f16x8*)(vl_ + dl_ * 128 + ((hi2 * 16) ^ vs_));       \
      f16x8 v1 = *(const f16x8*)(vl_ + dl_ * 128 + ((64 + hi2 * 16) ^ vs_));  \
      __builtin_amdgcn_s_setprio(1);                                          \
      o[(H) * 8 + j_] = MFMA16(pa[0], v0, o[(H) * 8 + j_]);                   \
      o[(H) * 8 + j_] = MFMA16(pa[1], v1, o[(H) * 8 + j_]);                   \
      __builtin_amdgcn_s_setprio(0);                                          \
    } } while (0)

  // ---- prologue: mask -> LDS, Q hi+lo -> regs, stage kt0.h0, full drain ----
  {
    int4 mv = *(const int4*)&maskg[bb * SEQ + tid * 4];
    *(int4*)&Msk[tid * 4] = mv;
  }
  f16x8 fq[16], fql[16];
  #pragma unroll
  for (int st = 0; st < 16; st++) {
    fq[st]  = *(const f16x8*)(qhi + st * 32 + hi2 * 8);
    fql[st] = *(const f16x8*)(qlo + st * 32 + hi2 * 8);
  }
  STAGE_K(0, 0, 0);
  __syncthreads();

  f32x4 o[16];
  #pragma unroll
  for (int f = 0; f < 16; f++)
    #pragma unroll
    for (int i = 0; i < 4; i++) o[f][i] = 0.f;

  float m_run[4], l_run[4], m_runP = -3.0e38f;
  #pragma unroll
  for (int i = 0; i < 4; i++) { m_run[i] = -3.0e38f; l_run[i] = 0.f; }

  #pragma unroll 1
  for (int kt = 0; kt < 32; kt++) {
    const int key0 = kt * 64;

    // ---- P1: issue K.h1 + V.h0; publish Ks[0] (prev E drained); QK h0 ----
    STAGE_K(kt, 1, 1);                    // A
    STAGE_V(kt, 0, 0);                    // C
    VM_BAR(8);                            // drains E(prev) -> Ks[0] ready

    f32x4 S[2];
    #pragma unroll
    for (int f = 0; f < 2; f++)
      #pragma unroll
      for (int i = 0; i < 4; i++) S[f][i] = 0.f;
    QK_HALF(0, 0);

    // ---- P2: publish Ks[1]; QK h1; issue V.h1 + K'.h0; local softmax ----
    VM_BAR(4);                            // drains A -> Ks[1] ready
    const int ms0 = Msk[key0 + kw * 32 + lo4];
    const int ms1 = Msk[key0 + kw * 32 + 16 + lo4];
    QK_HALF(1, 1);

    STAGE_V(kt, 1, 1);                    // D
    STAGE_K(kt + 1, 0, 0);                // E (kt=31 overruns into VT: benign)

    #pragma unroll
    for (int i = 0; i < 4; i++) {
      if (!ms0) S[0][i] = -1.0e9f;
      if (!ms1) S[1][i] = -1.0e9f;
      float mx = fmaxf(S[0][i], S[1][i]);
      #pragma unroll
      for (int off = 1; off < 16; off <<= 1)
        mx = fmaxf(mx, __shfl_xor(mx, off, 64));
      float p0 = __expf(S[0][i] - mx);
      float p1 = __expf(S[1][i] - mx);
      int row = qw*16 + hi2*4 + i;
      int swz = (row & 7) << 4;
      int b0  = (row*128 + (kw*32 + lo4)*2) ^ swz;
      int b1  = (row*128 + (kw*32 + 16 + lo4)*2) ^ swz;
      *(_Float16*)((char*)P + b0) = (_Float16)p0;
      *(_Float16*)((char*)P + b1) = (_Float16)p1;
      float ps = p0 + p1;
      #pragma unroll
      for (int off = 1; off < 16; off <<= 1) ps += __shfl_xor(ps, off, 64);
      if (lo4 == 0) { pmax[kw][row] = mx; psum[kw][row] = ps; }
    }

    // ---- P3: publish Vst[0] + P + stats ----
    VM_LGKM_BAR(8);                       // drains C -> Vst[0]; lgkm -> P/stats

    // ---- P4: merge stats, rescale o, scaled pa; PV h0; publish Vst[1]; PV h1
    float oscale[4];
    #pragma unroll
    for (int i = 0; i < 4; i++) {
      int row = qw*16 + hi2*4 + i;
      float m0 = pmax[0][row], m1 = pmax[1][row];
      float s0 = psum[0][row], s1 = psum[1][row];
      float mn = fmaxf(m_run[i], fmaxf(m0, m1));
      oscale[i] = __expf(m_run[i] - mn);
      l_run[i] = l_run[i] * oscale[i]
               + __expf(m0 - mn) * s0 + __expf(m1 - mn) * s1;
      m_run[i] = mn;
    }
    #pragma unroll
    for (int f = 0; f < 16; f++)
      #pragma unroll
      for (int i = 0; i < 4; i++) o[f][i] *= oscale[i];

    f16x8 pa[2];
    {
      const int prow = qw*16 + lo4;
      float m0p = pmax[0][prow], m1p = pmax[1][prow];
      float mnp = fmaxf(m_runP, fmaxf(m0p, m1p));
      m_runP = mnp;
      _Float16 c0 = (_Float16)__expf(m0p - mnp);
      _Float16 c1 = (_Float16)__expf(m1p - mnp);
      const int psw = (prow & 7) << 4;
      pa[0] = *(const f16x8*)((const char*)P + prow*128 + ((hi2*16) ^ psw));
      pa[1] = *(const f16x8*)((const char*)P + prow*128 + ((64 + hi2*16) ^ psw));
      pa[0] = pa[0] * c0;
      pa[1] = pa[1] * c1;
    }

    PV_HALF(0, 0);
    VM_BAR(4);                            // drains D -> Vst[1] ready (E stays)
    PV_HALF(1, 1);
  }
#undef STAGE_K
#undef STAGE_V
#undef QK_HALF
#undef PV_HALF

  asm volatile("s_waitcnt vmcnt(0)" ::: "memory");

  // ---- epilogue: normalize and store (overwrites block's own Q region) ----
  #pragma unroll
  for (int i = 0; i < 4; i++) {
    float inv = 1.0f / l_run[i];
    int rowg = bb * SEQ + q0 + qw*16 + hi2*4 + i;
    #pragma unroll
    for (int h = 0; h < 2; h++)
      #pragma unroll
      for (int j = 0; j < 8; j++) {
        int d = h*256 + j*32 + kw*16 + lo4;
        dout[(size_t)rowg * 512 + d] = o[h*8 + j][i] * inv;
      }
  }
}

extern "C" void kernel_launch(void* const* d_in, const int* in_sizes, int n_in,
                              void* d_out, int out_size, void* d_ws, size_t ws_size,
                              hipStream_t stream)
{
  const float* x    = (const float*)d_in[0];
  const float* Wq   = (const float*)d_in[1];
  const float* Wk   = (const float*)d_in[2];
  const float* Wv   = (const float*)d_in[3];
  const int*   mask = (const int*)d_in[4];

  _Float16* wsh = (_Float16*)d_ws;
  _Float16* KF = wsh;                  //  8,388,608 halfs (K fp16 [b*t][d])
  _Float16* VT = wsh + 8388608;        //  8,388,608 halfs (V^T fp16 [b][d][t])
  _Float16* WT = wsh + 16777216;       //  1,572,864 halfs -> 36.7 MB total

  wprep<<<1536, 256, 0, stream>>>(Wq, Wk, Wv, WT);

  dim3 pgrid(4, 128, 3);
  proj_v3<<<pgrid, 256, 0, stream>>>(x, WT, KF, VT, (_Float16*)d_out);

  flash_v4<<<256, 512, 0, stream>>>(KF, VT, mask, (float*)d_out);
}

// Round 10
// 353.675 us; speedup vs baseline: 1.5054x; 1.1319x over previous
//
#include <hip/hip_runtime.h>
#include <hip/hip_bf16.h>
#include <cstddef>
#include <cstdint>

#define BATCH 8
#define SEQ   2048
#define DEMB  1024
#define DQ    512

typedef __attribute__((ext_vector_type(8))) _Float16 f16x8;
typedef __attribute__((ext_vector_type(4))) float f32x4;

#define MFMA16(a, b, c) __builtin_amdgcn_mfma_f32_16x16x32_f16((a), (b), (c), 0, 0, 0)

#define GLDS16(gp, lp) __builtin_amdgcn_global_load_lds(                      \
    (const __attribute__((address_space(1))) void*)(gp),                      \
    (__attribute__((address_space(3))) void*)(lp), 16, 0, 0)

#define VM_BAR(N)                                                             \
  asm volatile("s_waitcnt vmcnt(" #N ")\n\ts_barrier" ::: "memory")
#define VM_LGKM_BAR(N)                                                        \
  asm volatile("s_waitcnt vmcnt(" #N ") lgkmcnt(0)\n\ts_barrier" ::: "memory")

// ---------------------------------------------------------------------------
// X fp32 -> fp16 (one pass; halves proj's 12x re-read traffic).
// ---------------------------------------------------------------------------
__global__ __launch_bounds__(256) void xprep(
    const float* __restrict__ x, _Float16* __restrict__ xh)
{
  size_t i = ((size_t)blockIdx.x * 256 + threadIdx.x) * 8;
  float4 a = *(const float4*)&x[i];
  float4 b = *(const float4*)&x[i + 4];
  f16x8 h;
  h[0] = (_Float16)a.x; h[1] = (_Float16)a.y;
  h[2] = (_Float16)a.z; h[3] = (_Float16)a.w;
  h[4] = (_Float16)b.x; h[5] = (_Float16)b.y;
  h[6] = (_Float16)b.z; h[7] = (_Float16)b.w;
  *(f16x8*)&xh[i] = h;
}

// ---------------------------------------------------------------------------
// Transpose W (fp32 [k][n]) -> WT (fp16 [n][k]) for all three weight mats.
// ---------------------------------------------------------------------------
__global__ __launch_bounds__(256) void wprep(
    const float* __restrict__ Wq, const float* __restrict__ Wk,
    const float* __restrict__ Wv, _Float16* __restrict__ wt)
{
  int qidx = blockIdx.x * 256 + threadIdx.x;     // 0 .. 3*1024*128-1
  int w   = qidx >> 17;
  int rem = qidx & 131071;
  int k   = rem >> 7;                            // 0..1023
  int n   = (rem & 127) * 4;                     // 0..508
  const float* W = (w == 0) ? Wq : (w == 1) ? Wk : Wv;
  float4 v = *(const float4*)&W[(size_t)k * DQ + n];
  _Float16* dst = wt + (size_t)w * (DQ * DEMB);
  dst[(size_t)(n + 0) * DEMB + k] = (_Float16)v.x;
  dst[(size_t)(n + 1) * DEMB + k] = (_Float16)v.y;
  dst[(size_t)(n + 2) * DEMB + k] = (_Float16)v.z;
  dst[(size_t)(n + 3) * DEMB + k] = (_Float16)v.w;
}

// ---------------------------------------------------------------------------
// Projection GEMM (r6 structure verbatim; X path now reads pre-converted
// fp16 Xh — staging mirrors the W path, no cvt in loop).
// C[16384,512] = X[16384,1024]*W.  BM=128, BN=128, BK=32, 4 waves of 64x64.
// Q packed into d_out in 64-row groups (hi 64x512 then lo 64x512).
// ---------------------------------------------------------------------------
__global__ __launch_bounds__(256) void proj_f16(
    const _Float16* __restrict__ xh, const _Float16* __restrict__ wt,
    _Float16* __restrict__ kf, _Float16* __restrict__ vt,
    _Float16* __restrict__ qpack)
{
  const int w  = blockIdx.z;
  const int mt = blockIdx.y, nt = blockIdx.x;

  __shared__ _Float16 Xs[128][40];
  __shared__ _Float16 Ws[128][40];

  const int tid  = threadIdx.x;
  const int wave = tid >> 6, l = tid & 63;
  const int wm = wave >> 1, wn = wave & 1;
  const int lo4 = l & 15, hi2 = l >> 4;

  f32x4 acc[4][4];
  #pragma unroll
  for (int mf = 0; mf < 4; mf++)
    #pragma unroll
    for (int nf = 0; nf < 4; nf++)
      #pragma unroll
      for (int i = 0; i < 4; i++) acc[mf][nf][i] = 0.f;

  const int    srow  = tid >> 1;
  const int    skh   = (tid & 1) * 16;
  const size_t xbase = (size_t)(mt * 128 + srow) * DEMB + skh;
  const size_t wbase = (size_t)w * (DQ * DEMB) + (size_t)(nt * 128 + srow) * DEMB + skh;

  #pragma unroll 1
  for (int k0 = 0; k0 < DEMB; k0 += 32) {
    // stage X tile (fp16, two 16B loads like the W path)
    *(f16x8*)&Xs[srow][skh]     = *(const f16x8*)&xh[xbase + k0];
    *(f16x8*)&Xs[srow][skh + 8] = *(const f16x8*)&xh[xbase + k0 + 8];
    // stage W tile (already fp16 [n][k])
    *(f16x8*)&Ws[srow][skh]     = *(const f16x8*)&wt[wbase + k0];
    *(f16x8*)&Ws[srow][skh + 8] = *(const f16x8*)&wt[wbase + k0 + 8];
    __syncthreads();

    f16x8 a[4], bfr[4];
    #pragma unroll
    for (int mf = 0; mf < 4; mf++)
      a[mf] = *(const f16x8*)&Xs[wm*64 + mf*16 + lo4][hi2*8];
    #pragma unroll
    for (int nf = 0; nf < 4; nf++)
      bfr[nf] = *(const f16x8*)&Ws[wn*64 + nf*16 + lo4][hi2*8];
    #pragma unroll
    for (int mf = 0; mf < 4; mf++)
      #pragma unroll
      for (int nf = 0; nf < 4; nf++)
        acc[mf][nf] = MFMA16(a[mf], bfr[nf], acc[mf][nf]);
    __syncthreads();
  }

  const int mb = mt * 128 + wm * 64;
  const int nb = nt * 128 + wn * 64;
  #pragma unroll
  for (int mf = 0; mf < 4; mf++)
    #pragma unroll
    for (int nf = 0; nf < 4; nf++)
      #pragma unroll
      for (int i = 0; i < 4; i++) {
        int m = mb + mf*16 + hi2*4 + i;
        int n = nb + nf*16 + lo4;
        float val = acc[mf][nf][i];
        if (w == 0) {
          _Float16 h  = (_Float16)val;
          _Float16 lo = (_Float16)(val - (float)h);
          size_t base = (size_t)(m >> 6) * 65536 + (size_t)(m & 63) * 512 + n;
          qpack[base]         = h;
          qpack[base + 32768] = lo;
        } else if (w == 1) {
          kf[(size_t)m * 512 + n] = (_Float16)val;
        } else {
          vt[(size_t)(m >> 11) * (512 * 2048) + (size_t)n * 2048 + (m & 2047)]
              = (_Float16)val;
        }
      }
}

// ---------------------------------------------------------------------------
// Flash attention v4 (r6 VERBATIM — best measured: 258µs).
// Counted-vmcnt 4-phase pipeline, merged single-exchange softmax, Q hi+lo in
// registers, mask in LDS; per-kt global traffic is exclusively
// global_load_lds (exact vmcnt accounting 8/4/8+lgkm/4).
// ---------------------------------------------------------------------------
__global__ __launch_bounds__(512, 2) void flash_v4(
    const _Float16* __restrict__ kfp, const _Float16* __restrict__ vtp,
    const int* __restrict__ maskg,
    float* dout)                          // aliases Q storage - no restrict
{
  const int bb = blockIdx.x & 7;          // batch -> XCD pin
  const int qt = blockIdx.x >> 3;         // 0..31
  const int q0 = qt * 64;

  const int tid = threadIdx.x;
  const int w = tid >> 6, l = tid & 63;
  const int qw = w & 3;                   // 16-row group
  const int kw = w >> 2;                  // 0..1
  const int lo4 = l & 15, hi2 = l >> 4;

  __shared__ _Float16 Kst[2][64][256];    // 64KB, src-swizzled
  __shared__ _Float16 Vst[2][256][64];    // 64KB, src-swizzled
  __shared__ _Float16 P[64 * 64];         // 8KB, XOR-swizzled rows
  __shared__ int      Msk[2048];          // 8KB
  __shared__ float pmax[2][64], psum[2][64];

  const _Float16* qpk = (const _Float16*)dout + (size_t)(bb * 32 + qt) * 65536;
  const char*     kb  = (const char*)(kfp + (size_t)bb * SEQ * 512);
  const char*     vtb = (const char*)(vtp + (size_t)bb * (512 * 2048));

  const _Float16* qhi = qpk + (size_t)(qw * 16 + lo4) * 512;
  const _Float16* qlo = qhi + 32768;

#define STAGE_K(KT, H, B) do {                                                \
    const char* kg_ = kb + (size_t)(KT) * 64 * 1024;                          \
    char* lb_ = (char*)&Kst[(B)][0][0];                                       \
    _Pragma("unroll")                                                         \
    for (int i_ = 0; i_ < 4; i_++) {                                          \
      int D_ = i_ * 8192 + tid * 16;                                          \
      int row_ = D_ >> 9, cb_ = D_ & 511;                                     \
      GLDS16(kg_ + (size_t)row_ * 1024 + (H) * 512 +                          \
                 (cb_ ^ ((row_ & 7) << 4)),                                   \
             lb_ + D_);                                                       \
    } } while (0)

#define STAGE_V(KT, H, B) do {                                                \
    const char* vg_ = vtb + (size_t)(KT) * 128;                               \
    char* lb_ = (char*)&Vst[(B)][0][0];                                       \
    _Pragma("unroll")                                                         \
    for (int i_ = 0; i_ < 4; i_++) {                                          \
      int D_ = i_ * 8192 + tid * 16;                                          \
      int row_ = D_ >> 7, cb_ = D_ & 127;                                     \
      GLDS16(vg_ + (size_t)((H) * 256 + row_) * 4096 +                        \
                 (cb_ ^ ((row_ & 7) << 4)),                                   \
             lb_ + D_);                                                       \
    } } while (0)

#define QK_HALF(H, B) do {                                                    \
    const char* kl_ = (const char*)&Kst[(B)][0][0];                           \
    const int r0_ = kw * 32 + lo4, r1_ = r0_ + 16;                            \
    const int sw_ = (lo4 & 7) << 4;                                           \
    _Pragma("unroll")                                                         \
    for (int s_ = 0; s_ < 8; s_++) {                                          \
      const int dby_ = (s_ * 32 + hi2 * 8) * 2;                               \
      f16x8 k0 = *(const f16x8*)(kl_ + r0_ * 512 + (dby_ ^ sw_));             \
      f16x8 k1 = *(const f16x8*)(kl_ + r1_ * 512 + (dby_ ^ sw_));             \
      __builtin_amdgcn_s_setprio(1);                                          \
      S[0] = MFMA16(fq[(H) * 8 + s_], k0, S[0]);                              \
      S[1] = MFMA16(fq[(H) * 8 + s_], k1, S[1]);                              \
      S[0] = MFMA16(fql[(H) * 8 + s_], k0, S[0]);                             \
      S[1] = MFMA16(fql[(H) * 8 + s_], k1, S[1]);                             \
      __builtin_amdgcn_s_setprio(0);                                          \
    } } while (0)

#define PV_HALF(H, B) do {                                                    \
    const char* vl_ = (const char*)&Vst[(B)][0][0];                           \
    _Pragma("unroll")                                                         \
    for (int j_ = 0; j_ < 8; j_++) {                                          \
      const int dl_ = j_ * 32 + kw * 16 + lo4;                                \
      const int vs_ = (dl_ & 7) << 4;                                         \
      f16x8 v0 = *(const f16x8*)(vl_ + dl_ * 128 + ((hi2 * 16) ^ vs_));       \
      f16x8 v1 = *(const f16x8*)(vl_ + dl_ * 128 + ((64 + hi2 * 16) ^ vs_));  \
      __builtin_amdgcn_s_setprio(1);                                          \
      o[(H) * 8 + j_] = MFMA16(pa[0], v0, o[(H) * 8 + j_]);                   \
      o[(H) * 8 + j_] = MFMA16(pa[1], v1, o[(H) * 8 + j_]);                   \
      __builtin_amdgcn_s_setprio(0);                                          \
    } } while (0)

  // ---- prologue: mask -> LDS, Q hi+lo -> regs, stage kt0.h0, full drain ----
  {
    int4 mv = *(const int4*)&maskg[bb * SEQ + tid * 4];
    *(int4*)&Msk[tid * 4] = mv;
  }
  f16x8 fq[16], fql[16];
  #pragma unroll
  for (int st = 0; st < 16; st++) {
    fq[st]  = *(const f16x8*)(qhi + st * 32 + hi2 * 8);
    fql[st] = *(const f16x8*)(qlo + st * 32 + hi2 * 8);
  }
  STAGE_K(0, 0, 0);
  __syncthreads();

  f32x4 o[16];
  #pragma unroll
  for (int f = 0; f < 16; f++)
    #pragma unroll
    for (int i = 0; i < 4; i++) o[f][i] = 0.f;

  float m_run[4], l_run[4], m_runP = -3.0e38f;
  #pragma unroll
  for (int i = 0; i < 4; i++) { m_run[i] = -3.0e38f; l_run[i] = 0.f; }

  #pragma unroll 1
  for (int kt = 0; kt < 32; kt++) {
    const int key0 = kt * 64;

    // ---- P1: issue K.h1 + V.h0; publish Ks[0] (prev E drained); QK h0 ----
    STAGE_K(kt, 1, 1);                    // A
    STAGE_V(kt, 0, 0);                    // C
    VM_BAR(8);                            // drains E(prev) -> Ks[0] ready

    f32x4 S[2];
    #pragma unroll
    for (int f = 0; f < 2; f++)
      #pragma unroll
      for (int i = 0; i < 4; i++) S[f][i] = 0.f;
    QK_HALF(0, 0);

    // ---- P2: publish Ks[1]; QK h1; issue V.h1 + K'.h0; local softmax ----
    VM_BAR(4);                            // drains A -> Ks[1] ready
    const int ms0 = Msk[key0 + kw * 32 + lo4];
    const int ms1 = Msk[key0 + kw * 32 + 16 + lo4];
    QK_HALF(1, 1);

    STAGE_V(kt, 1, 1);                    // D
    STAGE_K(kt + 1, 0, 0);                // E (kt=31 overruns into VT: benign)

    #pragma unroll
    for (int i = 0; i < 4; i++) {
      if (!ms0) S[0][i] = -1.0e9f;
      if (!ms1) S[1][i] = -1.0e9f;
      float mx = fmaxf(S[0][i], S[1][i]);
      #pragma unroll
      for (int off = 1; off < 16; off <<= 1)
        mx = fmaxf(mx, __shfl_xor(mx, off, 64));
      float p0 = __expf(S[0][i] - mx);
      float p1 = __expf(S[1][i] - mx);
      int row = qw*16 + hi2*4 + i;
      int swz = (row & 7) << 4;
      int b0  = (row*128 + (kw*32 + lo4)*2) ^ swz;
      int b1  = (row*128 + (kw*32 + 16 + lo4)*2) ^ swz;
      *(_Float16*)((char*)P + b0) = (_Float16)p0;
      *(_Float16*)((char*)P + b1) = (_Float16)p1;
      float ps = p0 + p1;
      #pragma unroll
      for (int off = 1; off < 16; off <<= 1) ps += __shfl_xor(ps, off, 64);
      if (lo4 == 0) { pmax[kw][row] = mx; psum[kw][row] = ps; }
    }

    // ---- P3: publish Vst[0] + P + stats ----
    VM_LGKM_BAR(8);                       // drains C -> Vst[0]; lgkm -> P/stats

    // ---- P4: merge stats, rescale o, scaled pa; PV h0; publish Vst[1]; PV h1
    float oscale[4];
    #pragma unroll
    for (int i = 0; i < 4; i++) {
      int row = qw*16 + hi2*4 + i;
      float m0 = pmax[0][row], m1 = pmax[1][row];
      float s0 = psum[0][row], s1 = psum[1][row];
      float mn = fmaxf(m_run[i], fmaxf(m0, m1));
      oscale[i] = __expf(m_run[i] - mn);
      l_run[i] = l_run[i] * oscale[i]
               + __expf(m0 - mn) * s0 + __expf(m1 - mn) * s1;
      m_run[i] = mn;
    }
    #pragma unroll
    for (int f = 0; f < 16; f++)
      #pragma unroll
      for (int i = 0; i < 4; i++) o[f][i] *= oscale[i];

    f16x8 pa[2];
    {
      const int prow = qw*16 + lo4;
      float m0p = pmax[0][prow], m1p = pmax[1][prow];
      float mnp = fmaxf(m_runP, fmaxf(m0p, m1p));
      m_runP = mnp;
      _Float16 c0 = (_Float16)__expf(m0p - mnp);
      _Float16 c1 = (_Float16)__expf(m1p - mnp);
      const int psw = (prow & 7) << 4;
      pa[0] = *(const f16x8*)((const char*)P + prow*128 + ((hi2*16) ^ psw));
      pa[1] = *(const f16x8*)((const char*)P + prow*128 + ((64 + hi2*16) ^ psw));
      pa[0] = pa[0] * c0;
      pa[1] = pa[1] * c1;
    }

    PV_HALF(0, 0);
    VM_BAR(4);                            // drains D -> Vst[1] ready (E stays)
    PV_HALF(1, 1);
  }
#undef STAGE_K
#undef STAGE_V
#undef QK_HALF
#undef PV_HALF

  asm volatile("s_waitcnt vmcnt(0)" ::: "memory");

  // ---- epilogue: normalize and store (overwrites block's own Q region) ----
  #pragma unroll
  for (int i = 0; i < 4; i++) {
    float inv = 1.0f / l_run[i];
    int rowg = bb * SEQ + q0 + qw*16 + hi2*4 + i;
    #pragma unroll
    for (int h = 0; h < 2; h++)
      #pragma unroll
      for (int j = 0; j < 8; j++) {
        int d = h*256 + j*32 + kw*16 + lo4;
        dout[(size_t)rowg * 512 + d] = o[h*8 + j][i] * inv;
      }
  }
}

extern "C" void kernel_launch(void* const* d_in, const int* in_sizes, int n_in,
                              void* d_out, int out_size, void* d_ws, size_t ws_size,
                              hipStream_t stream)
{
  const float* x    = (const float*)d_in[0];
  const float* Wq   = (const float*)d_in[1];
  const float* Wk   = (const float*)d_in[2];
  const float* Wv   = (const float*)d_in[3];
  const int*   mask = (const int*)d_in[4];

  _Float16* wsh = (_Float16*)d_ws;
  _Float16* KF = wsh;                  //  8,388,608 halfs (K fp16 [b*t][d])
  _Float16* VT = wsh +  8388608;       //  8,388,608 halfs (V^T fp16 [b][d][t])
  _Float16* WT = wsh + 16777216;       //  1,572,864 halfs (W^T fp16)
  _Float16* XH = wsh + 18350080;       // 16,777,216 halfs (X fp16) -> 70.3 MB

  xprep<<<8192, 256, 0, stream>>>(x, XH);
  wprep<<<1536, 256, 0, stream>>>(Wq, Wk, Wv, WT);

  dim3 pgrid(4, 128, 3);
  proj_f16<<<pgrid, 256, 0, stream>>>(XH, WT, KF, VT, (_Float16*)d_out);

  flash_v4<<<256, 512, 0, stream>>>(KF, VT, mask, (float*)d_out);
}

// Round 11
// 274.695 us; speedup vs baseline: 1.9382x; 1.2875x over previous
//
#include <hip/hip_runtime.h>
#include <hip/hip_bf16.h>
#include <cstddef>
#include <cstdint>

#define BATCH 8
#define SEQ   2048
#define DEMB  1024
#define DQ    512

typedef __attribute__((ext_vector_type(8))) _Float16 f16x8;
typedef __attribute__((ext_vector_type(4))) float f32x4;

#define MFMA16(a, b, c) __builtin_amdgcn_mfma_f32_16x16x32_f16((a), (b), (c), 0, 0, 0)

#define GLDS16(gp, lp) __builtin_amdgcn_global_load_lds(                      \
    (const __attribute__((address_space(1))) void*)(gp),                      \
    (__attribute__((address_space(3))) void*)(lp), 16, 0, 0)

#define VM_BAR(N)                                                             \
  asm volatile("s_waitcnt vmcnt(" #N ")\n\ts_barrier" ::: "memory")
#define VM_LGKM_BAR(N)                                                        \
  asm volatile("s_waitcnt vmcnt(" #N ") lgkmcnt(0)\n\ts_barrier" ::: "memory")

// ---------------------------------------------------------------------------
// Mask prefix-scan per batch: pidx[b][t] = (mask ? compacted index : -1),
// cnt[b] = number of unmasked keys. Order-preserving.
// ---------------------------------------------------------------------------
__global__ __launch_bounds__(256) void mprep(
    const int* __restrict__ maskg, int* __restrict__ pidx,
    int* __restrict__ cnt)
{
  const int b = blockIdx.x;
  const int tid = threadIdx.x;
  __shared__ int tsum[256];
  int mv[8], s = 0;
  #pragma unroll
  for (int j = 0; j < 8; j++) {
    mv[j] = maskg[b * SEQ + tid * 8 + j];
    s += mv[j];
  }
  tsum[tid] = s;
  __syncthreads();
  for (int d = 1; d < 256; d <<= 1) {
    int v = (tid >= d) ? tsum[tid - d] : 0;
    __syncthreads();
    tsum[tid] += v;
    __syncthreads();
  }
  if (tid == 255) cnt[b] = tsum[255];
  int run = tsum[tid] - s;               // exclusive prefix
  #pragma unroll
  for (int j = 0; j < 8; j++) {
    pidx[b * SEQ + tid * 8 + j] = mv[j] ? run : -1;
    run += mv[j];
  }
}

// ---------------------------------------------------------------------------
// X fp32 -> fp16 (one pass; halves proj's 12x re-read traffic).
// ---------------------------------------------------------------------------
__global__ __launch_bounds__(256) void xprep(
    const float* __restrict__ x, _Float16* __restrict__ xh)
{
  size_t i = ((size_t)blockIdx.x * 256 + threadIdx.x) * 8;
  float4 a = *(const float4*)&x[i];
  float4 b = *(const float4*)&x[i + 4];
  f16x8 h;
  h[0] = (_Float16)a.x; h[1] = (_Float16)a.y;
  h[2] = (_Float16)a.z; h[3] = (_Float16)a.w;
  h[4] = (_Float16)b.x; h[5] = (_Float16)b.y;
  h[6] = (_Float16)b.z; h[7] = (_Float16)b.w;
  *(f16x8*)&xh[i] = h;
}

// ---------------------------------------------------------------------------
// Transpose W (fp32 [k][n]) -> WT (fp16 [n][k]) for all three weight mats.
// ---------------------------------------------------------------------------
__global__ __launch_bounds__(256) void wprep(
    const float* __restrict__ Wq, const float* __restrict__ Wk,
    const float* __restrict__ Wv, _Float16* __restrict__ wt)
{
  int qidx = blockIdx.x * 256 + threadIdx.x;     // 0 .. 3*1024*128-1
  int w   = qidx >> 17;
  int rem = qidx & 131071;
  int k   = rem >> 7;                            // 0..1023
  int n   = (rem & 127) * 4;                     // 0..508
  const float* W = (w == 0) ? Wq : (w == 1) ? Wk : Wv;
  float4 v = *(const float4*)&W[(size_t)k * DQ + n];
  _Float16* dst = wt + (size_t)w * (DQ * DEMB);
  dst[(size_t)(n + 0) * DEMB + k] = (_Float16)v.x;
  dst[(size_t)(n + 1) * DEMB + k] = (_Float16)v.y;
  dst[(size_t)(n + 2) * DEMB + k] = (_Float16)v.z;
  dst[(size_t)(n + 3) * DEMB + k] = (_Float16)v.w;
}

// ---------------------------------------------------------------------------
// Projection GEMM (r10 structure; K/V epilogues now scatter through pidx so
// K and V^T are COMPACTED to unmasked keys, order-preserving).
// Q packed into d_out in 64-row groups (hi 64x512 then lo 64x512).
// ---------------------------------------------------------------------------
__global__ __launch_bounds__(256) void proj_f16(
    const _Float16* __restrict__ xh, const _Float16* __restrict__ wt,
    const int* __restrict__ pidx,
    _Float16* __restrict__ kf, _Float16* __restrict__ vt,
    _Float16* __restrict__ qpack)
{
  const int w  = blockIdx.z;
  const int mt = blockIdx.y, nt = blockIdx.x;

  __shared__ _Float16 Xs[128][40];
  __shared__ _Float16 Ws[128][40];

  const int tid  = threadIdx.x;
  const int wave = tid >> 6, l = tid & 63;
  const int wm = wave >> 1, wn = wave & 1;
  const int lo4 = l & 15, hi2 = l >> 4;

  f32x4 acc[4][4];
  #pragma unroll
  for (int mf = 0; mf < 4; mf++)
    #pragma unroll
    for (int nf = 0; nf < 4; nf++)
      #pragma unroll
      for (int i = 0; i < 4; i++) acc[mf][nf][i] = 0.f;

  const int    srow  = tid >> 1;
  const int    skh   = (tid & 1) * 16;
  const size_t xbase = (size_t)(mt * 128 + srow) * DEMB + skh;
  const size_t wbase = (size_t)w * (DQ * DEMB) + (size_t)(nt * 128 + srow) * DEMB + skh;

  #pragma unroll 1
  for (int k0 = 0; k0 < DEMB; k0 += 32) {
    *(f16x8*)&Xs[srow][skh]     = *(const f16x8*)&xh[xbase + k0];
    *(f16x8*)&Xs[srow][skh + 8] = *(const f16x8*)&xh[xbase + k0 + 8];
    *(f16x8*)&Ws[srow][skh]     = *(const f16x8*)&wt[wbase + k0];
    *(f16x8*)&Ws[srow][skh + 8] = *(const f16x8*)&wt[wbase + k0 + 8];
    __syncthreads();

    f16x8 a[4], bfr[4];
    #pragma unroll
    for (int mf = 0; mf < 4; mf++)
      a[mf] = *(const f16x8*)&Xs[wm*64 + mf*16 + lo4][hi2*8];
    #pragma unroll
    for (int nf = 0; nf < 4; nf++)
      bfr[nf] = *(const f16x8*)&Ws[wn*64 + nf*16 + lo4][hi2*8];
    #pragma unroll
    for (int mf = 0; mf < 4; mf++)
      #pragma unroll
      for (int nf = 0; nf < 4; nf++)
        acc[mf][nf] = MFMA16(a[mf], bfr[nf], acc[mf][nf]);
    __syncthreads();
  }

  const int mb = mt * 128 + wm * 64;
  const int nb = nt * 128 + wn * 64;
  #pragma unroll
  for (int mf = 0; mf < 4; mf++)
    #pragma unroll
    for (int nf = 0; nf < 4; nf++)
      #pragma unroll
      for (int i = 0; i < 4; i++) {
        int m = mb + mf*16 + hi2*4 + i;
        int n = nb + nf*16 + lo4;
        float val = acc[mf][nf][i];
        if (w == 0) {
          _Float16 h  = (_Float16)val;
          _Float16 lo = (_Float16)(val - (float)h);
          size_t base = (size_t)(m >> 6) * 65536 + (size_t)(m & 63) * 512 + n;
          qpack[base]         = h;
          qpack[base + 32768] = lo;
        } else if (w == 1) {
          int d_ = pidx[m];
          if (d_ >= 0)
            kf[((size_t)((m >> 11) << 11) + d_) * 512 + n] = (_Float16)val;
        } else {
          int d_ = pidx[m];
          if (d_ >= 0)
            vt[(size_t)(m >> 11) * (512 * 2048) + (size_t)n * 2048 + d_]
                = (_Float16)val;
        }
      }
}

// ---------------------------------------------------------------------------
// Flash attention v4c: r6's validated counted-vmcnt 4-phase pipeline, run on
// COMPACTED K/V (unmasked keys only, ~half the tiles). Mask logic replaced by
// a tail compare key_idx >= cnt. Everything else identical to the 258µs
// configuration.
// ---------------------------------------------------------------------------
__global__ __launch_bounds__(512, 2) void flash_v4(
    const _Float16* __restrict__ kfp, const _Float16* __restrict__ vtp,
    const int* __restrict__ cntg,
    float* dout)                          // aliases Q storage - no restrict
{
  const int bb = blockIdx.x & 7;          // batch -> XCD pin
  const int qt = blockIdx.x >> 3;         // 0..31
  const int q0 = qt * 64;

  const int tid = threadIdx.x;
  const int w = tid >> 6, l = tid & 63;
  const int qw = w & 3;                   // 16-row group
  const int kw = w >> 2;                  // 0..1
  const int lo4 = l & 15, hi2 = l >> 4;

  __shared__ _Float16 Kst[2][64][256];    // 64KB, src-swizzled
  __shared__ _Float16 Vst[2][256][64];    // 64KB, src-swizzled
  __shared__ _Float16 P[64 * 64];         // 8KB, XOR-swizzled rows
  __shared__ float pmax[2][64], psum[2][64];

  const _Float16* qpk = (const _Float16*)dout + (size_t)(bb * 32 + qt) * 65536;
  const char*     kb  = (const char*)(kfp + (size_t)bb * SEQ * 512);
  const char*     vtb = (const char*)(vtp + (size_t)bb * (512 * 2048));

  const _Float16* qhi = qpk + (size_t)(qw * 16 + lo4) * 512;
  const _Float16* qlo = qhi + 32768;

  const int cnt = cntg[bb];
  const int nkt = (cnt + 63) >> 6;        // ~16-17 tiles typical

#define STAGE_K(KT, H, B) do {                                                \
    const char* kg_ = kb + (size_t)(KT) * 64 * 1024;                          \
    char* lb_ = (char*)&Kst[(B)][0][0];                                       \
    _Pragma("unroll")                                                         \
    for (int i_ = 0; i_ < 4; i_++) {                                          \
      int D_ = i_ * 8192 + tid * 16;                                          \
      int row_ = D_ >> 9, cb_ = D_ & 511;                                     \
      GLDS16(kg_ + (size_t)row_ * 1024 + (H) * 512 +                          \
                 (cb_ ^ ((row_ & 7) << 4)),                                   \
             lb_ + D_);                                                       \
    } } while (0)

#define STAGE_V(KT, H, B) do {                                                \
    const char* vg_ = vtb + (size_t)(KT) * 128;                               \
    char* lb_ = (char*)&Vst[(B)][0][0];                                       \
    _Pragma("unroll")                                                         \
    for (int i_ = 0; i_ < 4; i_++) {                                          \
      int D_ = i_ * 8192 + tid * 16;                                          \
      int row_ = D_ >> 7, cb_ = D_ & 127;                                     \
      GLDS16(vg_ + (size_t)((H) * 256 + row_) * 4096 +                        \
                 (cb_ ^ ((row_ & 7) << 4)),                                   \
             lb_ + D_);                                                       \
    } } while (0)

#define QK_HALF(H, B) do {                                                    \
    const char* kl_ = (const char*)&Kst[(B)][0][0];                           \
    const int r0_ = kw * 32 + lo4, r1_ = r0_ + 16;                            \
    const int sw_ = (lo4 & 7) << 4;                                           \
    _Pragma("unroll")                                                         \
    for (int s_ = 0; s_ < 8; s_++) {                                          \
      const int dby_ = (s_ * 32 + hi2 * 8) * 2;                               \
      f16x8 k0 = *(const f16x8*)(kl_ + r0_ * 512 + (dby_ ^ sw_));             \
      f16x8 k1 = *(const f16x8*)(kl_ + r1_ * 512 + (dby_ ^ sw_));             \
      __builtin_amdgcn_s_setprio(1);                                          \
      S[0] = MFMA16(fq[(H) * 8 + s_], k0, S[0]);                              \
      S[1] = MFMA16(fq[(H) * 8 + s_], k1, S[1]);                              \
      S[0] = MFMA16(fql[(H) * 8 + s_], k0, S[0]);                             \
      S[1] = MFMA16(fql[(H) * 8 + s_], k1, S[1]);                             \
      __builtin_amdgcn_s_setprio(0);                                          \
    } } while (0)

#define PV_HALF(H, B) do {                                                    \
    const char* vl_ = (const char*)&Vst[(B)][0][0];                           \
    _Pragma("unroll")                                                         \
    for (int j_ = 0; j_ < 8; j_++) {                                          \
      const int dl_ = j_ * 32 + kw * 16 + lo4;                                \
      const int vs_ = (dl_ & 7) << 4;                                         \
      f16x8 v0 = *(const f16x8*)(vl_ + dl_ * 128 + ((hi2 * 16) ^ vs_));       \
      f16x8 v1 = *(const f16x8*)(vl_ + dl_ * 128 + ((64 + hi2 * 16) ^ vs_));  \
      __builtin_amdgcn_s_setprio(1);                                          \
      o[(H) * 8 + j_] = MFMA16(pa[0], v0, o[(H) * 8 + j_]);                   \
      o[(H) * 8 + j_] = MFMA16(pa[1], v1, o[(H) * 8 + j_]);                   \
      __builtin_amdgcn_s_setprio(0);                                          \
    } } while (0)

  // ---- prologue: Q hi+lo -> regs, stage kt0.h0, full drain ----
  f16x8 fq[16], fql[16];
  #pragma unroll
  for (int st = 0; st < 16; st++) {
    fq[st]  = *(const f16x8*)(qhi + st * 32 + hi2 * 8);
    fql[st] = *(const f16x8*)(qlo + st * 32 + hi2 * 8);
  }
  STAGE_K(0, 0, 0);
  __syncthreads();

  f32x4 o[16];
  #pragma unroll
  for (int f = 0; f < 16; f++)
    #pragma unroll
    for (int i = 0; i < 4; i++) o[f][i] = 0.f;

  float m_run[4], l_run[4], m_runP = -3.0e38f;
  #pragma unroll
  for (int i = 0; i < 4; i++) { m_run[i] = -3.0e38f; l_run[i] = 0.f; }

  const int ki0 = kw * 32 + lo4;          // this lane's key cols in tile
  const int ki1 = ki0 + 16;

  #pragma unroll 1
  for (int kt = 0; kt < nkt; kt++) {
    const int key0 = kt * 64;

    // ---- P1: issue K.h1 + V.h0; publish Ks[0] (prev E drained); QK h0 ----
    STAGE_K(kt, 1, 1);                    // A
    STAGE_V(kt, 0, 0);                    // C
    VM_BAR(8);                            // drains E(prev) -> Ks[0] ready

    f32x4 S[2];
    #pragma unroll
    for (int f = 0; f < 2; f++)
      #pragma unroll
      for (int i = 0; i < 4; i++) S[f][i] = 0.f;
    QK_HALF(0, 0);

    // ---- P2: publish Ks[1]; QK h1; issue V.h1 + K'.h0; local softmax ----
    VM_BAR(4);                            // drains A -> Ks[1] ready
    QK_HALF(1, 1);

    STAGE_V(kt, 1, 1);                    // D
    STAGE_K(kt + 1, 0, 0);                // E (last kt overruns: benign)

    const bool t0 = (key0 + ki0 >= cnt);  // tail mask (compacted)
    const bool t1 = (key0 + ki1 >= cnt);
    #pragma unroll
    for (int i = 0; i < 4; i++) {
      if (t0) S[0][i] = -1.0e9f;
      if (t1) S[1][i] = -1.0e9f;
      float mx = fmaxf(S[0][i], S[1][i]);
      #pragma unroll
      for (int off = 1; off < 16; off <<= 1)
        mx = fmaxf(mx, __shfl_xor(mx, off, 64));
      float p0 = __expf(S[0][i] - mx);
      float p1 = __expf(S[1][i] - mx);
      int row = qw*16 + hi2*4 + i;
      int swz = (row & 7) << 4;
      int b0  = (row*128 + (kw*32 + lo4)*2) ^ swz;
      int b1  = (row*128 + (kw*32 + 16 + lo4)*2) ^ swz;
      *(_Float16*)((char*)P + b0) = (_Float16)p0;
      *(_Float16*)((char*)P + b1) = (_Float16)p1;
      float ps = p0 + p1;
      #pragma unroll
      for (int off = 1; off < 16; off <<= 1) ps += __shfl_xor(ps, off, 64);
      if (lo4 == 0) { pmax[kw][row] = mx; psum[kw][row] = ps; }
    }

    // ---- P3: publish Vst[0] + P + stats ----
    VM_LGKM_BAR(8);                       // drains C -> Vst[0]; lgkm -> P/stats

    // ---- P4: merge stats, rescale o, scaled pa; PV h0; publish Vst[1]; PV h1
    float oscale[4];
    #pragma unroll
    for (int i = 0; i < 4; i++) {
      int row = qw*16 + hi2*4 + i;
      float m0 = pmax[0][row], m1 = pmax[1][row];
      float s0 = psum[0][row], s1 = psum[1][row];
      float mn = fmaxf(m_run[i], fmaxf(m0, m1));
      oscale[i] = __expf(m_run[i] - mn);
      l_run[i] = l_run[i] * oscale[i]
               + __expf(m0 - mn) * s0 + __expf(m1 - mn) * s1;
      m_run[i] = mn;
    }
    #pragma unroll
    for (int f = 0; f < 16; f++)
      #pragma unroll
      for (int i = 0; i < 4; i++) o[f][i] *= oscale[i];

    f16x8 pa[2];
    {
      const int prow = qw*16 + lo4;
      float m0p = pmax[0][prow], m1p = pmax[1][prow];
      float mnp = fmaxf(m_runP, fmaxf(m0p, m1p));
      m_runP = mnp;
      _Float16 c0 = (_Float16)__expf(m0p - mnp);
      _Float16 c1 = (_Float16)__expf(m1p - mnp);
      const int psw = (prow & 7) << 4;
      pa[0] = *(const f16x8*)((const char*)P + prow*128 + ((hi2*16) ^ psw));
      pa[1] = *(const f16x8*)((const char*)P + prow*128 + ((64 + hi2*16) ^ psw));
      pa[0] = pa[0] * c0;
      pa[1] = pa[1] * c1;
    }

    PV_HALF(0, 0);
    VM_BAR(4);                            // drains D -> Vst[1] ready (E stays)
    PV_HALF(1, 1);
  }
#undef STAGE_K
#undef STAGE_V
#undef QK_HALF
#undef PV_HALF

  asm volatile("s_waitcnt vmcnt(0)" ::: "memory");

  // ---- epilogue: normalize and store (overwrites block's own Q region) ----
  #pragma unroll
  for (int i = 0; i < 4; i++) {
    float inv = 1.0f / l_run[i];
    int rowg = bb * SEQ + q0 + qw*16 + hi2*4 + i;
    #pragma unroll
    for (int h = 0; h < 2; h++)
      #pragma unroll
      for (int j = 0; j < 8; j++) {
        int d = h*256 + j*32 + kw*16 + lo4;
        dout[(size_t)rowg * 512 + d] = o[h*8 + j][i] * inv;
      }
  }
}

extern "C" void kernel_launch(void* const* d_in, const int* in_sizes, int n_in,
                              void* d_out, int out_size, void* d_ws, size_t ws_size,
                              hipStream_t stream)
{
  const float* x    = (const float*)d_in[0];
  const float* Wq   = (const float*)d_in[1];
  const float* Wk   = (const float*)d_in[2];
  const float* Wv   = (const float*)d_in[3];
  const int*   mask = (const int*)d_in[4];

  _Float16* wsh = (_Float16*)d_ws;
  _Float16* KF = wsh;                  //  8,388,608 halfs (K fp16 compacted)
  _Float16* VT = wsh +  8388608;       //  8,388,608 halfs (V^T fp16 compacted)
  _Float16* WT = wsh + 16777216;       //  1,572,864 halfs (W^T fp16)
  _Float16* XH = wsh + 18350080;       // 16,777,216 halfs (X fp16)
  int* PIDX    = (int*)(wsh + 35127296);   // 16,384 ints
  int* CNT     = PIDX + 16384;             // 8 ints -> ~70.4 MB total

  mprep<<<BATCH, 256, 0, stream>>>(mask, PIDX, CNT);
  xprep<<<8192, 256, 0, stream>>>(x, XH);
  wprep<<<1536, 256, 0, stream>>>(Wq, Wk, Wv, WT);

  dim3 pgrid(4, 128, 3);
  proj_f16<<<pgrid, 256, 0, stream>>>(XH, WT, PIDX, KF, VT, (_Float16*)d_out);

  flash_v4<<<256, 512, 0, stream>>>(KF, VT, CNT, (float*)d_out);
}

// Round 12
// 256.306 us; speedup vs baseline: 2.0772x; 1.0717x over previous
//
#include <hip/hip_runtime.h>
#include <hip/hip_bf16.h>
#include <cstddef>
#include <cstdint>

#define BATCH 8
#define SEQ   2048
#define DEMB  1024
#define DQ    512

typedef __attribute__((ext_vector_type(8))) _Float16 f16x8;
typedef __attribute__((ext_vector_type(4))) float f32x4;

#define MFMA16(a, b, c) __builtin_amdgcn_mfma_f32_16x16x32_f16((a), (b), (c), 0, 0, 0)

#define GLDS16(gp, lp) __builtin_amdgcn_global_load_lds(                      \
    (const __attribute__((address_space(1))) void*)(gp),                      \
    (__attribute__((address_space(3))) void*)(lp), 16, 0, 0)

#define VM_BAR(N)                                                             \
  asm volatile("s_waitcnt vmcnt(" #N ")\n\ts_barrier" ::: "memory")
#define VM_LGKM_BAR(N)                                                        \
  asm volatile("s_waitcnt vmcnt(" #N ") lgkmcnt(0)\n\ts_barrier" ::: "memory")

// ---------------------------------------------------------------------------
// Merged prep: blocks [0,8192) xprep; [8192,9728) wprep; [9728,9736) mprep.
// One launch -> mprep/wprep hide under the BW-bound xprep.
// ---------------------------------------------------------------------------
__global__ __launch_bounds__(256) void prep_all(
    const float* __restrict__ x, _Float16* __restrict__ xh,
    const float* __restrict__ Wq, const float* __restrict__ Wk,
    const float* __restrict__ Wv, _Float16* __restrict__ wt,
    const int* __restrict__ maskg, int* __restrict__ pidx,
    int* __restrict__ cnt)
{
  const int bid = blockIdx.x;
  const int tid = threadIdx.x;

  if (bid < 8192) {
    // ---- xprep: X fp32 -> fp16 ----
    size_t i = ((size_t)bid * 256 + tid) * 8;
    float4 a = *(const float4*)&x[i];
    float4 b = *(const float4*)&x[i + 4];
    f16x8 h;
    h[0] = (_Float16)a.x; h[1] = (_Float16)a.y;
    h[2] = (_Float16)a.z; h[3] = (_Float16)a.w;
    h[4] = (_Float16)b.x; h[5] = (_Float16)b.y;
    h[6] = (_Float16)b.z; h[7] = (_Float16)b.w;
    *(f16x8*)&xh[i] = h;
  } else if (bid < 9728) {
    // ---- wprep: W fp32 [k][n] -> fp16 [n][k] ----
    int qidx = (bid - 8192) * 256 + tid;
    int w   = qidx >> 17;
    int rem = qidx & 131071;
    int k   = rem >> 7;
    int n   = (rem & 127) * 4;
    const float* W = (w == 0) ? Wq : (w == 1) ? Wk : Wv;
    float4 v = *(const float4*)&W[(size_t)k * DQ + n];
    _Float16* dst = wt + (size_t)w * (DQ * DEMB);
    dst[(size_t)(n + 0) * DEMB + k] = (_Float16)v.x;
    dst[(size_t)(n + 1) * DEMB + k] = (_Float16)v.y;
    dst[(size_t)(n + 2) * DEMB + k] = (_Float16)v.z;
    dst[(size_t)(n + 3) * DEMB + k] = (_Float16)v.w;
  } else {
    // ---- mprep: per-batch order-preserving prefix scan of mask ----
    const int b = bid - 9728;
    __shared__ int tsum[256];
    int mv[8], s = 0;
    #pragma unroll
    for (int j = 0; j < 8; j++) {
      mv[j] = maskg[b * SEQ + tid * 8 + j];
      s += mv[j];
    }
    tsum[tid] = s;
    __syncthreads();
    for (int d = 1; d < 256; d <<= 1) {
      int v = (tid >= d) ? tsum[tid - d] : 0;
      __syncthreads();
      tsum[tid] += v;
      __syncthreads();
    }
    if (tid == 255) cnt[b] = tsum[255];
    int run = tsum[tid] - s;             // exclusive prefix
    #pragma unroll
    for (int j = 0; j < 8; j++) {
      pidx[b * SEQ + tid * 8 + j] = mv[j] ? run : -1;
      run += mv[j];
    }
  }
}

// ---------------------------------------------------------------------------
// Projection GEMM: BM=128, BN=256, BK=32, 512 threads = 8 waves (2m x 4n);
// per-wave shape/accumulators/LDS pattern identical to the validated r10
// kernel (bit-identical output). X re-read passes drop 12 -> 6.
// K/V epilogues scatter through pidx (compaction). Q packed into d_out in
// 64-row groups (hi 64x512 then lo 64x512).
// ---------------------------------------------------------------------------
__global__ __launch_bounds__(512) void proj_f16(
    const _Float16* __restrict__ xh, const _Float16* __restrict__ wt,
    const int* __restrict__ pidx,
    _Float16* __restrict__ kf, _Float16* __restrict__ vt,
    _Float16* __restrict__ qpack)
{
  const int w  = blockIdx.z;
  const int mt = blockIdx.y, nt = blockIdx.x;

  __shared__ _Float16 Xs[128][40];   // 10KB
  __shared__ _Float16 Ws[256][40];   // 20KB

  const int tid  = threadIdx.x;
  const int wave = tid >> 6, l = tid & 63;
  const int wm = wave >> 2;          // 0..1  (64-row group)
  const int wn = wave & 3;           // 0..3  (64-col group)
  const int lo4 = l & 15, hi2 = l >> 4;

  f32x4 acc[4][4];
  #pragma unroll
  for (int mf = 0; mf < 4; mf++)
    #pragma unroll
    for (int nf = 0; nf < 4; nf++)
      #pragma unroll
      for (int i = 0; i < 4; i++) acc[mf][nf][i] = 0.f;

  // X staging: 128 rows x 32 k = 512 f16x8 -> 1 per thread
  const int    xsrow = tid >> 2;
  const int    xskh  = (tid & 3) * 8;
  const size_t xbase = (size_t)(mt * 128 + xsrow) * DEMB + xskh;
  // W staging: 256 rows x 32 k = 1024 f16x8 -> 2 per thread
  const int    wsrow = tid >> 1;
  const int    wskh  = (tid & 1) * 16;
  const size_t wbase = (size_t)w * (DQ * DEMB)
                     + (size_t)(nt * 256 + wsrow) * DEMB + wskh;

  #pragma unroll 1
  for (int k0 = 0; k0 < DEMB; k0 += 32) {
    *(f16x8*)&Xs[xsrow][xskh]    = *(const f16x8*)&xh[xbase + k0];
    *(f16x8*)&Ws[wsrow][wskh]    = *(const f16x8*)&wt[wbase + k0];
    *(f16x8*)&Ws[wsrow][wskh+8]  = *(const f16x8*)&wt[wbase + k0 + 8];
    __syncthreads();

    f16x8 a[4], bfr[4];
    #pragma unroll
    for (int mf = 0; mf < 4; mf++)
      a[mf] = *(const f16x8*)&Xs[wm*64 + mf*16 + lo4][hi2*8];
    #pragma unroll
    for (int nf = 0; nf < 4; nf++)
      bfr[nf] = *(const f16x8*)&Ws[wn*64 + nf*16 + lo4][hi2*8];
    #pragma unroll
    for (int mf = 0; mf < 4; mf++)
      #pragma unroll
      for (int nf = 0; nf < 4; nf++)
        acc[mf][nf] = MFMA16(a[mf], bfr[nf], acc[mf][nf]);
    __syncthreads();
  }

  const int mb = mt * 128 + wm * 64;
  const int nb = nt * 256 + wn * 64;
  #pragma unroll
  for (int mf = 0; mf < 4; mf++)
    #pragma unroll
    for (int nf = 0; nf < 4; nf++)
      #pragma unroll
      for (int i = 0; i < 4; i++) {
        int m = mb + mf*16 + hi2*4 + i;
        int n = nb + nf*16 + lo4;
        float val = acc[mf][nf][i];
        if (w == 0) {
          _Float16 h  = (_Float16)val;
          _Float16 lo = (_Float16)(val - (float)h);
          size_t base = (size_t)(m >> 6) * 65536 + (size_t)(m & 63) * 512 + n;
          qpack[base]         = h;
          qpack[base + 32768] = lo;
        } else if (w == 1) {
          int d_ = pidx[m];
          if (d_ >= 0)
            kf[((size_t)((m >> 11) << 11) + d_) * 512 + n] = (_Float16)val;
        } else {
          int d_ = pidx[m];
          if (d_ >= 0)
            vt[(size_t)(m >> 11) * (512 * 2048) + (size_t)n * 2048 + d_]
                = (_Float16)val;
        }
      }
}

// ---------------------------------------------------------------------------
// Flash attention v4c (r11 VERBATIM — 157µs): counted-vmcnt 4-phase pipeline
// on COMPACTED K/V; tail compare replaces the mask.
// ---------------------------------------------------------------------------
__global__ __launch_bounds__(512, 2) void flash_v4(
    const _Float16* __restrict__ kfp, const _Float16* __restrict__ vtp,
    const int* __restrict__ cntg,
    float* dout)                          // aliases Q storage - no restrict
{
  const int bb = blockIdx.x & 7;          // batch -> XCD pin
  const int qt = blockIdx.x >> 3;         // 0..31
  const int q0 = qt * 64;

  const int tid = threadIdx.x;
  const int w = tid >> 6, l = tid & 63;
  const int qw = w & 3;                   // 16-row group
  const int kw = w >> 2;                  // 0..1
  const int lo4 = l & 15, hi2 = l >> 4;

  __shared__ _Float16 Kst[2][64][256];    // 64KB, src-swizzled
  __shared__ _Float16 Vst[2][256][64];    // 64KB, src-swizzled
  __shared__ _Float16 P[64 * 64];         // 8KB, XOR-swizzled rows
  __shared__ float pmax[2][64], psum[2][64];

  const _Float16* qpk = (const _Float16*)dout + (size_t)(bb * 32 + qt) * 65536;
  const char*     kb  = (const char*)(kfp + (size_t)bb * SEQ * 512);
  const char*     vtb = (const char*)(vtp + (size_t)bb * (512 * 2048));

  const _Float16* qhi = qpk + (size_t)(qw * 16 + lo4) * 512;
  const _Float16* qlo = qhi + 32768;

  const int cnt = cntg[bb];
  const int nkt = (cnt + 63) >> 6;

#define STAGE_K(KT, H, B) do {                                                \
    const char* kg_ = kb + (size_t)(KT) * 64 * 1024;                          \
    char* lb_ = (char*)&Kst[(B)][0][0];                                       \
    _Pragma("unroll")                                                         \
    for (int i_ = 0; i_ < 4; i_++) {                                          \
      int D_ = i_ * 8192 + tid * 16;                                          \
      int row_ = D_ >> 9, cb_ = D_ & 511;                                     \
      GLDS16(kg_ + (size_t)row_ * 1024 + (H) * 512 +                          \
                 (cb_ ^ ((row_ & 7) << 4)),                                   \
             lb_ + D_);                                                       \
    } } while (0)

#define STAGE_V(KT, H, B) do {                                                \
    const char* vg_ = vtb + (size_t)(KT) * 128;                               \
    char* lb_ = (char*)&Vst[(B)][0][0];                                       \
    _Pragma("unroll")                                                         \
    for (int i_ = 0; i_ < 4; i_++) {                                          \
      int D_ = i_ * 8192 + tid * 16;                                          \
      int row_ = D_ >> 7, cb_ = D_ & 127;                                     \
      GLDS16(vg_ + (size_t)((H) * 256 + row_) * 4096 +                        \
                 (cb_ ^ ((row_ & 7) << 4)),                                   \
             lb_ + D_);                                                       \
    } } while (0)

#define QK_HALF(H, B) do {                                                    \
    const char* kl_ = (const char*)&Kst[(B)][0][0];                           \
    const int r0_ = kw * 32 + lo4, r1_ = r0_ + 16;                            \
    const int sw_ = (lo4 & 7) << 4;                                           \
    _Pragma("unroll")                                                         \
    for (int s_ = 0; s_ < 8; s_++) {                                          \
      const int dby_ = (s_ * 32 + hi2 * 8) * 2;                               \
      f16x8 k0 = *(const f16x8*)(kl_ + r0_ * 512 + (dby_ ^ sw_));             \
      f16x8 k1 = *(const f16x8*)(kl_ + r1_ * 512 + (dby_ ^ sw_));             \
      __builtin_amdgcn_s_setprio(1);                                          \
      S[0] = MFMA16(fq[(H) * 8 + s_], k0, S[0]);                              \
      S[1] = MFMA16(fq[(H) * 8 + s_], k1, S[1]);                              \
      S[0] = MFMA16(fql[(H) * 8 + s_], k0, S[0]);                             \
      S[1] = MFMA16(fql[(H) * 8 + s_], k1, S[1]);                             \
      __builtin_amdgcn_s_setprio(0);                                          \
    } } while (0)

#define PV_HALF(H, B) do {                                                    \
    const char* vl_ = (const char*)&Vst[(B)][0][0];                           \
    _Pragma("unroll")                                                         \
    for (int j_ = 0; j_ < 8; j_++) {                                          \
      const int dl_ = j_ * 32 + kw * 16 + lo4;                                \
      const int vs_ = (dl_ & 7) << 4;                                         \
      f16x8 v0 = *(const f16x8*)(vl_ + dl_ * 128 + ((hi2 * 16) ^ vs_));       \
      f16x8 v1 = *(const f16x8*)(vl_ + dl_ * 128 + ((64 + hi2 * 16) ^ vs_));  \
      __builtin_amdgcn_s_setprio(1);                                          \
      o[(H) * 8 + j_] = MFMA16(pa[0], v0, o[(H) * 8 + j_]);                   \
      o[(H) * 8 + j_] = MFMA16(pa[1], v1, o[(H) * 8 + j_]);                   \
      __builtin_amdgcn_s_setprio(0);                                          \
    } } while (0)

  // ---- prologue: Q hi+lo -> regs, stage kt0.h0, full drain ----
  f16x8 fq[16], fql[16];
  #pragma unroll
  for (int st = 0; st < 16; st++) {
    fq[st]  = *(const f16x8*)(qhi + st * 32 + hi2 * 8);
    fql[st] = *(const f16x8*)(qlo + st * 32 + hi2 * 8);
  }
  STAGE_K(0, 0, 0);
  __syncthreads();

  f32x4 o[16];
  #pragma unroll
  for (int f = 0; f < 16; f++)
    #pragma unroll
    for (int i = 0; i < 4; i++) o[f][i] = 0.f;

  float m_run[4], l_run[4], m_runP = -3.0e38f;
  #pragma unroll
  for (int i = 0; i < 4; i++) { m_run[i] = -3.0e38f; l_run[i] = 0.f; }

  const int ki0 = kw * 32 + lo4;
  const int ki1 = ki0 + 16;

  #pragma unroll 1
  for (int kt = 0; kt < nkt; kt++) {
    const int key0 = kt * 64;

    // ---- P1: issue K.h1 + V.h0; publish Ks[0] (prev E drained); QK h0 ----
    STAGE_K(kt, 1, 1);                    // A
    STAGE_V(kt, 0, 0);                    // C
    VM_BAR(8);                            // drains E(prev) -> Ks[0] ready

    f32x4 S[2];
    #pragma unroll
    for (int f = 0; f < 2; f++)
      #pragma unroll
      for (int i = 0; i < 4; i++) S[f][i] = 0.f;
    QK_HALF(0, 0);

    // ---- P2: publish Ks[1]; QK h1; issue V.h1 + K'.h0; local softmax ----
    VM_BAR(4);                            // drains A -> Ks[1] ready
    QK_HALF(1, 1);

    STAGE_V(kt, 1, 1);                    // D
    STAGE_K(kt + 1, 0, 0);                // E (last kt overruns: benign)

    const bool t0 = (key0 + ki0 >= cnt);
    const bool t1 = (key0 + ki1 >= cnt);
    #pragma unroll
    for (int i = 0; i < 4; i++) {
      if (t0) S[0][i] = -1.0e9f;
      if (t1) S[1][i] = -1.0e9f;
      float mx = fmaxf(S[0][i], S[1][i]);
      #pragma unroll
      for (int off = 1; off < 16; off <<= 1)
        mx = fmaxf(mx, __shfl_xor(mx, off, 64));
      float p0 = __expf(S[0][i] - mx);
      float p1 = __expf(S[1][i] - mx);
      int row = qw*16 + hi2*4 + i;
      int swz = (row & 7) << 4;
      int b0  = (row*128 + (kw*32 + lo4)*2) ^ swz;
      int b1  = (row*128 + (kw*32 + 16 + lo4)*2) ^ swz;
      *(_Float16*)((char*)P + b0) = (_Float16)p0;
      *(_Float16*)((char*)P + b1) = (_Float16)p1;
      float ps = p0 + p1;
      #pragma unroll
      for (int off = 1; off < 16; off <<= 1) ps += __shfl_xor(ps, off, 64);
      if (lo4 == 0) { pmax[kw][row] = mx; psum[kw][row] = ps; }
    }

    // ---- P3: publish Vst[0] + P + stats ----
    VM_LGKM_BAR(8);                       // drains C -> Vst[0]; lgkm -> P/stats

    // ---- P4: merge stats, rescale o, scaled pa; PV h0; publish Vst[1]; PV h1
    float oscale[4];
    #pragma unroll
    for (int i = 0; i < 4; i++) {
      int row = qw*16 + hi2*4 + i;
      float m0 = pmax[0][row], m1 = pmax[1][row];
      float s0 = psum[0][row], s1 = psum[1][row];
      float mn = fmaxf(m_run[i], fmaxf(m0, m1));
      oscale[i] = __expf(m_run[i] - mn);
      l_run[i] = l_run[i] * oscale[i]
               + __expf(m0 - mn) * s0 + __expf(m1 - mn) * s1;
      m_run[i] = mn;
    }
    #pragma unroll
    for (int f = 0; f < 16; f++)
      #pragma unroll
      for (int i = 0; i < 4; i++) o[f][i] *= oscale[i];

    f16x8 pa[2];
    {
      const int prow = qw*16 + lo4;
      float m0p = pmax[0][prow], m1p = pmax[1][prow];
      float mnp = fmaxf(m_runP, fmaxf(m0p, m1p));
      m_runP = mnp;
      _Float16 c0 = (_Float16)__expf(m0p - mnp);
      _Float16 c1 = (_Float16)__expf(m1p - mnp);
      const int psw = (prow & 7) << 4;
      pa[0] = *(const f16x8*)((const char*)P + prow*128 + ((hi2*16) ^ psw));
      pa[1] = *(const f16x8*)((const char*)P + prow*128 + ((64 + hi2*16) ^ psw));
      pa[0] = pa[0] * c0;
      pa[1] = pa[1] * c1;
    }

    PV_HALF(0, 0);
    VM_BAR(4);                            // drains D -> Vst[1] ready (E stays)
    PV_HALF(1, 1);
  }
#undef STAGE_K
#undef STAGE_V
#undef QK_HALF
#undef PV_HALF

  asm volatile("s_waitcnt vmcnt(0)" ::: "memory");

  // ---- epilogue: normalize and store (overwrites block's own Q region) ----
  #pragma unroll
  for (int i = 0; i < 4; i++) {
    float inv = 1.0f / l_run[i];
    int rowg = bb * SEQ + q0 + qw*16 + hi2*4 + i;
    #pragma unroll
    for (int h = 0; h < 2; h++)
      #pragma unroll
      for (int j = 0; j < 8; j++) {
        int d = h*256 + j*32 + kw*16 + lo4;
        dout[(size_t)rowg * 512 + d] = o[h*8 + j][i] * inv;
      }
  }
}

extern "C" void kernel_launch(void* const* d_in, const int* in_sizes, int n_in,
                              void* d_out, int out_size, void* d_ws, size_t ws_size,
                              hipStream_t stream)
{
  const float* x    = (const float*)d_in[0];
  const float* Wq   = (const float*)d_in[1];
  const float* Wk   = (const float*)d_in[2];
  const float* Wv   = (const float*)d_in[3];
  const int*   mask = (const int*)d_in[4];

  _Float16* wsh = (_Float16*)d_ws;
  _Float16* KF = wsh;                  //  8,388,608 halfs (K fp16 compacted)
  _Float16* VT = wsh +  8388608;       //  8,388,608 halfs (V^T fp16 compacted)
  _Float16* WT = wsh + 16777216;       //  1,572,864 halfs (W^T fp16)
  _Float16* XH = wsh + 18350080;       // 16,777,216 halfs (X fp16)
  int* PIDX    = (int*)(wsh + 35127296);   // 16,384 ints
  int* CNT     = PIDX + 16384;             // 8 ints -> ~70.4 MB total

  prep_all<<<9736, 256, 0, stream>>>(x, XH, Wq, Wk, Wv, WT, mask, PIDX, CNT);

  dim3 pgrid(2, 128, 3);
  proj_f16<<<pgrid, 512, 0, stream>>>(XH, WT, PIDX, KF, VT, (_Float16*)d_out);

  flash_v4<<<256, 512, 0, stream>>>(KF, VT, CNT, (float*)d_out);
}

// Round 13
// 254.456 us; speedup vs baseline: 2.0923x; 1.0073x over previous
//
#include <hip/hip_runtime.h>
#include <hip/hip_bf16.h>
#include <cstddef>
#include <cstdint>

#define BATCH 8
#define SEQ   2048
#define DEMB  1024
#define DQ    512

typedef __attribute__((ext_vector_type(8))) _Float16 f16x8;
typedef __attribute__((ext_vector_type(4))) float f32x4;

#define MFMA16(a, b, c) __builtin_amdgcn_mfma_f32_16x16x32_f16((a), (b), (c), 0, 0, 0)

#define GLDS16(gp, lp) __builtin_amdgcn_global_load_lds(                      \
    (const __attribute__((address_space(1))) void*)(gp),                      \
    (__attribute__((address_space(3))) void*)(lp), 16, 0, 0)

#define VM_BAR(N)                                                             \
  asm volatile("s_waitcnt vmcnt(" #N ")\n\ts_barrier" ::: "memory")
#define VM_LGKM_BAR(N)                                                        \
  asm volatile("s_waitcnt vmcnt(" #N ") lgkmcnt(0)\n\ts_barrier" ::: "memory")
#define BAR()                                                                 \
  asm volatile("s_barrier" ::: "memory")

// ---------------------------------------------------------------------------
// Merged prep: blocks [0,8192) xprep; [8192,9728) wprep; [9728,9736) mprep.
// ---------------------------------------------------------------------------
__global__ __launch_bounds__(256) void prep_all(
    const float* __restrict__ x, _Float16* __restrict__ xh,
    const float* __restrict__ Wq, const float* __restrict__ Wk,
    const float* __restrict__ Wv, _Float16* __restrict__ wt,
    const int* __restrict__ maskg, int* __restrict__ pidx,
    int* __restrict__ cnt)
{
  const int bid = blockIdx.x;
  const int tid = threadIdx.x;

  if (bid < 8192) {
    size_t i = ((size_t)bid * 256 + tid) * 8;
    float4 a = *(const float4*)&x[i];
    float4 b = *(const float4*)&x[i + 4];
    f16x8 h;
    h[0] = (_Float16)a.x; h[1] = (_Float16)a.y;
    h[2] = (_Float16)a.z; h[3] = (_Float16)a.w;
    h[4] = (_Float16)b.x; h[5] = (_Float16)b.y;
    h[6] = (_Float16)b.z; h[7] = (_Float16)b.w;
    *(f16x8*)&xh[i] = h;
  } else if (bid < 9728) {
    int qidx = (bid - 8192) * 256 + tid;
    int w   = qidx >> 17;
    int rem = qidx & 131071;
    int k   = rem >> 7;
    int n   = (rem & 127) * 4;
    const float* W = (w == 0) ? Wq : (w == 1) ? Wk : Wv;
    float4 v = *(const float4*)&W[(size_t)k * DQ + n];
    _Float16* dst = wt + (size_t)w * (DQ * DEMB);
    dst[(size_t)(n + 0) * DEMB + k] = (_Float16)v.x;
    dst[(size_t)(n + 1) * DEMB + k] = (_Float16)v.y;
    dst[(size_t)(n + 2) * DEMB + k] = (_Float16)v.z;
    dst[(size_t)(n + 3) * DEMB + k] = (_Float16)v.w;
  } else {
    const int b = bid - 9728;
    __shared__ int tsum[256];
    int mv[8], s = 0;
    #pragma unroll
    for (int j = 0; j < 8; j++) {
      mv[j] = maskg[b * SEQ + tid * 8 + j];
      s += mv[j];
    }
    tsum[tid] = s;
    __syncthreads();
    for (int d = 1; d < 256; d <<= 1) {
      int v = (tid >= d) ? tsum[tid - d] : 0;
      __syncthreads();
      tsum[tid] += v;
      __syncthreads();
    }
    if (tid == 255) cnt[b] = tsum[255];
    int run = tsum[tid] - s;
    #pragma unroll
    for (int j = 0; j < 8; j++) {
      pidx[b * SEQ + tid * 8 + j] = mv[j] ? run : -1;
      run += mv[j];
    }
  }
}

// ---------------------------------------------------------------------------
// Projection GEMM (r12 verbatim): BM=128, BN=256, BK=32, 512 threads.
// ---------------------------------------------------------------------------
__global__ __launch_bounds__(512) void proj_f16(
    const _Float16* __restrict__ xh, const _Float16* __restrict__ wt,
    const int* __restrict__ pidx,
    _Float16* __restrict__ kf, _Float16* __restrict__ vt,
    _Float16* __restrict__ qpack)
{
  const int w  = blockIdx.z;
  const int mt = blockIdx.y, nt = blockIdx.x;

  __shared__ _Float16 Xs[128][40];
  __shared__ _Float16 Ws[256][40];

  const int tid  = threadIdx.x;
  const int wave = tid >> 6, l = tid & 63;
  const int wm = wave >> 2;
  const int wn = wave & 3;
  const int lo4 = l & 15, hi2 = l >> 4;

  f32x4 acc[4][4];
  #pragma unroll
  for (int mf = 0; mf < 4; mf++)
    #pragma unroll
    for (int nf = 0; nf < 4; nf++)
      #pragma unroll
      for (int i = 0; i < 4; i++) acc[mf][nf][i] = 0.f;

  const int    xsrow = tid >> 2;
  const int    xskh  = (tid & 3) * 8;
  const size_t xbase = (size_t)(mt * 128 + xsrow) * DEMB + xskh;
  const int    wsrow = tid >> 1;
  const int    wskh  = (tid & 1) * 16;
  const size_t wbase = (size_t)w * (DQ * DEMB)
                     + (size_t)(nt * 256 + wsrow) * DEMB + wskh;

  #pragma unroll 1
  for (int k0 = 0; k0 < DEMB; k0 += 32) {
    *(f16x8*)&Xs[xsrow][xskh]    = *(const f16x8*)&xh[xbase + k0];
    *(f16x8*)&Ws[wsrow][wskh]    = *(const f16x8*)&wt[wbase + k0];
    *(f16x8*)&Ws[wsrow][wskh+8]  = *(const f16x8*)&wt[wbase + k0 + 8];
    __syncthreads();

    f16x8 a[4], bfr[4];
    #pragma unroll
    for (int mf = 0; mf < 4; mf++)
      a[mf] = *(const f16x8*)&Xs[wm*64 + mf*16 + lo4][hi2*8];
    #pragma unroll
    for (int nf = 0; nf < 4; nf++)
      bfr[nf] = *(const f16x8*)&Ws[wn*64 + nf*16 + lo4][hi2*8];
    #pragma unroll
    for (int mf = 0; mf < 4; mf++)
      #pragma unroll
      for (int nf = 0; nf < 4; nf++)
        acc[mf][nf] = MFMA16(a[mf], bfr[nf], acc[mf][nf]);
    __syncthreads();
  }

  const int mb = mt * 128 + wm * 64;
  const int nb = nt * 256 + wn * 64;
  #pragma unroll
  for (int mf = 0; mf < 4; mf++)
    #pragma unroll
    for (int nf = 0; nf < 4; nf++)
      #pragma unroll
      for (int i = 0; i < 4; i++) {
        int m = mb + mf*16 + hi2*4 + i;
        int n = nb + nf*16 + lo4;
        float val = acc[mf][nf][i];
        if (w == 0) {
          _Float16 h  = (_Float16)val;
          _Float16 lo = (_Float16)(val - (float)h);
          size_t base = (size_t)(m >> 6) * 65536 + (size_t)(m & 63) * 512 + n;
          qpack[base]         = h;
          qpack[base + 32768] = lo;
        } else if (w == 1) {
          int d_ = pidx[m];
          if (d_ >= 0)
            kf[((size_t)((m >> 11) << 11) + d_) * 512 + n] = (_Float16)val;
        } else {
          int d_ = pidx[m];
          if (d_ >= 0)
            vt[(size_t)(m >> 11) * (512 * 2048) + (size_t)n * 2048 + d_]
                = (_Float16)val;
        }
      }
}

// ---------------------------------------------------------------------------
// Flash attention v7: LAGGED-PV 3-barrier pipeline on compacted K/V.
// Same macros/tiles/swizzles/numerics as the validated r11 kernel; only the
// schedule changes: PV(kt-1) runs inside QK(kt)'s phases, stats merge lags
// one tile, P double-buffered. Barriers per kt: B1 vmcnt(8)+lgkm,
// B2 vmcnt(0), B3 plain. Every stage has >= 1 full phase of lead.
// ---------------------------------------------------------------------------
__global__ __launch_bounds__(512, 2) void flash_v7(
    const _Float16* __restrict__ kfp, const _Float16* __restrict__ vtp,
    const int* __restrict__ cntg,
    float* dout)                          // aliases Q storage - no restrict
{
  const int bb = blockIdx.x & 7;          // batch -> XCD pin
  const int qt = blockIdx.x >> 3;         // 0..31
  const int q0 = qt * 64;

  const int tid = threadIdx.x;
  const int w = tid >> 6, l = tid & 63;
  const int qw = w & 3;                   // 16-row group
  const int kw = w >> 2;                  // 0..1
  const int lo4 = l & 15, hi2 = l >> 4;

  __shared__ _Float16 Kst[2][64][256];    // 64KB, src-swizzled
  __shared__ _Float16 Vst[2][256][64];    // 64KB, src-swizzled
  __shared__ _Float16 P[2][64 * 64];      // 16KB, XOR-swizzled rows, dbuf
  __shared__ float pmax[2][64], psum[2][64];

  const _Float16* qpk = (const _Float16*)dout + (size_t)(bb * 32 + qt) * 65536;
  const char*     kb  = (const char*)(kfp + (size_t)bb * SEQ * 512);
  const char*     vtb = (const char*)(vtp + (size_t)bb * (512 * 2048));

  const _Float16* qhi = qpk + (size_t)(qw * 16 + lo4) * 512;
  const _Float16* qlo = qhi + 32768;

  const int cnt = cntg[bb];
  const int nkt = (cnt + 63) >> 6;

#define STAGE_K(KT, H, B) do {                                                \
    const char* kg_ = kb + (size_t)(KT) * 64 * 1024;                          \
    char* lb_ = (char*)&Kst[(B)][0][0];                                       \
    _Pragma("unroll")                                                         \
    for (int i_ = 0; i_ < 4; i_++) {                                          \
      int D_ = i_ * 8192 + tid * 16;                                          \
      int row_ = D_ >> 9, cb_ = D_ & 511;                                     \
      GLDS16(kg_ + (size_t)row_ * 1024 + (H) * 512 +                          \
                 (cb_ ^ ((row_ & 7) << 4)),                                   \
             lb_ + D_);                                                       \
    } } while (0)

#define STAGE_V(KT, H, B) do {                                                \
    const char* vg_ = vtb + (size_t)(KT) * 128;                               \
    char* lb_ = (char*)&Vst[(B)][0][0];                                       \
    _Pragma("unroll")                                                         \
    for (int i_ = 0; i_ < 4; i_++) {                                          \
      int D_ = i_ * 8192 + tid * 16;                                          \
      int row_ = D_ >> 7, cb_ = D_ & 127;                                     \
      GLDS16(vg_ + (size_t)((H) * 256 + row_) * 4096 +                        \
                 (cb_ ^ ((row_ & 7) << 4)),                                   \
             lb_ + D_);                                                       \
    } } while (0)

#define QK_HALF(H, B) do {                                                    \
    const char* kl_ = (const char*)&Kst[(B)][0][0];                           \
    const int r0_ = kw * 32 + lo4, r1_ = r0_ + 16;                            \
    const int sw_ = (lo4 & 7) << 4;                                           \
    _Pragma("unroll")                                                         \
    for (int s_ = 0; s_ < 8; s_++) {                                          \
      const int dby_ = (s_ * 32 + hi2 * 8) * 2;                               \
      f16x8 k0 = *(const f16x8*)(kl_ + r0_ * 512 + (dby_ ^ sw_));             \
      f16x8 k1 = *(const f16x8*)(kl_ + r1_ * 512 + (dby_ ^ sw_));             \
      __builtin_amdgcn_s_setprio(1);                                          \
      S[0] = MFMA16(fq[(H) * 8 + s_], k0, S[0]);                              \
      S[1] = MFMA16(fq[(H) * 8 + s_], k1, S[1]);                              \
      S[0] = MFMA16(fql[(H) * 8 + s_], k0, S[0]);                             \
      S[1] = MFMA16(fql[(H) * 8 + s_], k1, S[1]);                             \
      __builtin_amdgcn_s_setprio(0);                                          \
    } } while (0)

#define PV_HALF(H, B) do {                                                    \
    const char* vl_ = (const char*)&Vst[(B)][0][0];                           \
    _Pragma("unroll")                                                         \
    for (int j_ = 0; j_ < 8; j_++) {                                          \
      const int dl_ = j_ * 32 + kw * 16 + lo4;                                \
      const int vs_ = (dl_ & 7) << 4;                                         \
      f16x8 v0 = *(const f16x8*)(vl_ + dl_ * 128 + ((hi2 * 16) ^ vs_));       \
      f16x8 v1 = *(const f16x8*)(vl_ + dl_ * 128 + ((64 + hi2 * 16) ^ vs_));  \
      __builtin_amdgcn_s_setprio(1);                                          \
      o[(H) * 8 + j_] = MFMA16(pa[0], v0, o[(H) * 8 + j_]);                   \
      o[(H) * 8 + j_] = MFMA16(pa[1], v1, o[(H) * 8 + j_]);                   \
      __builtin_amdgcn_s_setprio(0);                                          \
    } } while (0)

  // MERGE(tile T, parity PB): merge T's stats into running state, rescale o,
  // build pa from P[PB] (identical math to r11's P4 block).
#define MERGE_PA(PB) do {                                                     \
    float oscale[4];                                                          \
    _Pragma("unroll")                                                         \
    for (int i = 0; i < 4; i++) {                                             \
      int row = qw*16 + hi2*4 + i;                                            \
      float m0 = pmax[0][row], m1 = pmax[1][row];                             \
      float s0 = psum[0][row], s1 = psum[1][row];                             \
      float mn = fmaxf(m_run[i], fmaxf(m0, m1));                              \
      oscale[i] = __expf(m_run[i] - mn);                                      \
      l_run[i] = l_run[i] * oscale[i]                                         \
               + __expf(m0 - mn) * s0 + __expf(m1 - mn) * s1;                 \
      m_run[i] = mn;                                                          \
    }                                                                         \
    _Pragma("unroll")                                                         \
    for (int f = 0; f < 16; f++)                                              \
      _Pragma("unroll")                                                       \
      for (int i = 0; i < 4; i++) o[f][i] *= oscale[i];                       \
    {                                                                         \
      const int prow = qw*16 + lo4;                                           \
      float m0p = pmax[0][prow], m1p = pmax[1][prow];                         \
      float mnp = fmaxf(m_runP, fmaxf(m0p, m1p));                             \
      m_runP = mnp;                                                           \
      _Float16 c0 = (_Float16)__expf(m0p - mnp);                              \
      _Float16 c1 = (_Float16)__expf(m1p - mnp);                              \
      const int psw = (prow & 7) << 4;                                        \
      const char* pb_ = (const char*)&P[(PB)][0];                             \
      pa[0] = *(const f16x8*)(pb_ + prow*128 + ((hi2*16) ^ psw));             \
      pa[1] = *(const f16x8*)(pb_ + prow*128 + ((64 + hi2*16) ^ psw));        \
      pa[0] = pa[0] * c0;                                                     \
      pa[1] = pa[1] * c1;                                                     \
    } } while (0)

  // ---- prologue: Q hi+lo -> regs; prime FIFO in steady order; full drain ----
  f16x8 fq[16], fql[16];
  #pragma unroll
  for (int st = 0; st < 16; st++) {
    fq[st]  = *(const f16x8*)(qhi + st * 32 + hi2 * 8);
    fql[st] = *(const f16x8*)(qlo + st * 32 + hi2 * 8);
  }
  STAGE_V(0, 0, 0);
  STAGE_K(0, 0, 0);
  STAGE_V(0, 1, 1);
  STAGE_K(0, 1, 1);
  __syncthreads();                        // full drain: Kst/Vst hold tile 0

  f32x4 o[16];
  #pragma unroll
  for (int f = 0; f < 16; f++)
    #pragma unroll
    for (int i = 0; i < 4; i++) o[f][i] = 0.f;

  float m_run[4], l_run[4], m_runP = -3.0e38f;
  #pragma unroll
  for (int i = 0; i < 4; i++) { m_run[i] = -3.0e38f; l_run[i] = 0.f; }

  const int ki0 = kw * 32 + lo4;
  const int ki1 = ki0 + 16;

  #pragma unroll 1
  for (int kt = 0; kt < nkt; kt++) {
    const int key0 = kt * 64;
    const int cur = kt & 1;

    // ---- B1: Kst[0]=Kh0(kt), Vst[0]=Vh0(kt-1) ready; P/stats published ----
    VM_LGKM_BAR(8);

    f32x4 S[2];
    #pragma unroll
    for (int f = 0; f < 2; f++)
      #pragma unroll
      for (int i = 0; i < 4; i++) S[f][i] = 0.f;

    f16x8 pa[2];
    if (kt) MERGE_PA(cur ^ 1);            // merge tile kt-1, build pa

    QK_HALF(0, 0);
    if (kt) PV_HALF(0, 0);                // V(kt-1).h0

    // ---- B2: Kst[1]=Kh1(kt), Vst[1]=Vh1(kt-1) ready ----
    VM_BAR(0);

    QK_HALF(1, 1);
    if (kt) PV_HALF(1, 1);                // V(kt-1).h1

    STAGE_V(kt, 0, 0);                    // I_B2: Vh0(kt) (kt=0: idempotent)
    STAGE_K(kt + 1, 0, 0);                //       Kh0(kt+1)

    // ---- softmax local (tile kt) -> P[cur], stats ----
    const bool t0 = (key0 + ki0 >= cnt);
    const bool t1 = (key0 + ki1 >= cnt);
    #pragma unroll
    for (int i = 0; i < 4; i++) {
      if (t0) S[0][i] = -1.0e9f;
      if (t1) S[1][i] = -1.0e9f;
      float mx = fmaxf(S[0][i], S[1][i]);
      #pragma unroll
      for (int off = 1; off < 16; off <<= 1)
        mx = fmaxf(mx, __shfl_xor(mx, off, 64));
      float p0 = __expf(S[0][i] - mx);
      float p1 = __expf(S[1][i] - mx);
      int row = qw*16 + hi2*4 + i;
      int swz = (row & 7) << 4;
      int b0  = (row*128 + (kw*32 + lo4)*2) ^ swz;
      int b1  = (row*128 + (kw*32 + 16 + lo4)*2) ^ swz;
      *(_Float16*)((char*)&P[cur][0] + b0) = (_Float16)p0;
      *(_Float16*)((char*)&P[cur][0] + b1) = (_Float16)p1;
      float ps = p0 + p1;
      #pragma unroll
      for (int off = 1; off < 16; off <<= 1) ps += __shfl_xor(ps, off, 64);
      if (lo4 == 0) { pmax[kw][row] = mx; psum[kw][row] = ps; }
    }

    // ---- B3: all PVh1/QKh1 reads done -> safe to overwrite Kst[1]/Vst[1] ----
    BAR();
    STAGE_V(kt, 1, 1);                    // I_B3: Vh1(kt)
    STAGE_K(kt + 1, 1, 1);                //       Kh1(kt+1)
  }
#undef STAGE_K
#undef STAGE_V
#undef QK_HALF

  // ---- epilogue: drain all; merge last tile; final PV; normalize/store ----
  asm volatile("s_waitcnt vmcnt(0) lgkmcnt(0)\n\ts_barrier" ::: "memory");
  {
    f16x8 pa[2];
    MERGE_PA((nkt - 1) & 1);
    PV_HALF(0, 0);                        // Vst holds V(nkt-1)
    PV_HALF(1, 1);
  }
#undef PV_HALF
#undef MERGE_PA

  #pragma unroll
  for (int i = 0; i < 4; i++) {
    float inv = 1.0f / l_run[i];
    int rowg = bb * SEQ + q0 + qw*16 + hi2*4 + i;
    #pragma unroll
    for (int h = 0; h < 2; h++)
      #pragma unroll
      for (int j = 0; j < 8; j++) {
        int d = h*256 + j*32 + kw*16 + lo4;
        dout[(size_t)rowg * 512 + d] = o[h*8 + j][i] * inv;
      }
  }
}

extern "C" void kernel_launch(void* const* d_in, const int* in_sizes, int n_in,
                              void* d_out, int out_size, void* d_ws, size_t ws_size,
                              hipStream_t stream)
{
  const float* x    = (const float*)d_in[0];
  const float* Wq   = (const float*)d_in[1];
  const float* Wk   = (const float*)d_in[2];
  const float* Wv   = (const float*)d_in[3];
  const int*   mask = (const int*)d_in[4];

  _Float16* wsh = (_Float16*)d_ws;
  _Float16* KF = wsh;                  //  8,388,608 halfs (K fp16 compacted)
  _Float16* VT = wsh +  8388608;       //  8,388,608 halfs (V^T fp16 compacted)
  _Float16* WT = wsh + 16777216;       //  1,572,864 halfs (W^T fp16)
  _Float16* XH = wsh + 18350080;       // 16,777,216 halfs (X fp16)
  int* PIDX    = (int*)(wsh + 35127296);   // 16,384 ints
  int* CNT     = PIDX + 16384;             // 8 ints -> ~70.4 MB total

  prep_all<<<9736, 256, 0, stream>>>(x, XH, Wq, Wk, Wv, WT, mask, PIDX, CNT);

  dim3 pgrid(2, 128, 3);
  proj_f16<<<pgrid, 512, 0, stream>>>(XH, WT, PIDX, KF, VT, (_Float16*)d_out);

  flash_v7<<<256, 512, 0, stream>>>(KF, VT, CNT, (float*)d_out);
}